// Round 1
// baseline (716.324 us; speedup 1.0000x reference)
//
#include <hip/hip_runtime.h>
#include <math.h>

#define DIM 384
#define HEADS 6
#define HEAD_DIM 64
#define HIDDEN 1536
#define BATCH 8
#define SEQ 2048
#define TOKENS (BATCH * SEQ)

typedef __bf16 bf16;
typedef __bf16 bf16x8 __attribute__((ext_vector_type(8)));
typedef float f32x4 __attribute__((ext_vector_type(4)));

// ---------------- weight conversion (fp32 -> bf16, all 6 weight matrices) ----
#define NW_QKV  (1152 * 384)
#define NW_PROJ (384 * 384)
#define NW_FC1  (1536 * 384)
#define NW_EYE  (1536 * 1536)
#define NW_FC2  (384 * 1536)
#define NW_TOTAL (NW_QKV + NW_PROJ + NW_FC1 + 2 * NW_EYE + NW_FC2)

__global__ void convert_weights(const float* __restrict__ qkv, const float* __restrict__ proj,
                                const float* __restrict__ fc1, const float* __restrict__ e1,
                                const float* __restrict__ e2, const float* __restrict__ fc2,
                                bf16* __restrict__ dst) {
    int i = blockIdx.x * 256 + threadIdx.x;
    int stride = gridDim.x * 256;
    for (; i < NW_TOTAL; i += stride) {
        int j = i;
        float v;
        if (j < NW_QKV) v = qkv[j];
        else if ((j -= NW_QKV) < NW_PROJ) v = proj[j];
        else if ((j -= NW_PROJ) < NW_FC1) v = fc1[j];
        else if ((j -= NW_FC1) < NW_EYE) v = e1[j];
        else if ((j -= NW_EYE) < NW_EYE) v = e2[j];
        else v = fc2[j - NW_EYE];
        dst[i] = (bf16)v;
    }
}

// ---------------- LayerNorm: fp32 in -> bf16 out, one wave per token ---------
__global__ __launch_bounds__(256) void ln_kernel(const float* __restrict__ x,
                                                 const float* __restrict__ w,
                                                 const float* __restrict__ b,
                                                 bf16* __restrict__ out) {
    int wave = threadIdx.x >> 6;
    int lane = threadIdx.x & 63;
    int t = blockIdx.x * 4 + wave;
    const float* xr = x + (size_t)t * DIM;
    float v[6];
    float s = 0.f;
#pragma unroll
    for (int i = 0; i < 6; i++) { v[i] = xr[lane + 64 * i]; s += v[i]; }
#pragma unroll
    for (int m = 1; m < 64; m <<= 1) s += __shfl_xor(s, m, 64);
    float mu = s * (1.f / DIM);
    float q = 0.f;
#pragma unroll
    for (int i = 0; i < 6; i++) { float d = v[i] - mu; q += d * d; }
#pragma unroll
    for (int m = 1; m < 64; m <<= 1) q += __shfl_xor(q, m, 64);
    float rstd = rsqrtf(q * (1.f / DIM) + 1e-5f);
    bf16* orow = out + (size_t)t * DIM;
#pragma unroll
    for (int i = 0; i < 6; i++) {
        int c = lane + 64 * i;
        orow[c] = (bf16)((v[i] - mu) * rstd * w[c] + b[c]);
    }
}

// ---------------- GEMM: C[M,N] = A[M,K] @ W[N,K]^T (+ epilogue) --------------
// EPI 0: plain -> bf16 out
// EPI 1: +bias -> bf16 out
// EPI 2: +bias, exact GELU -> bf16 out
// EPI 3: +bias, out_f32 = resid + v*gamma (layer-scale residual)
template <int EPI>
__global__ __launch_bounds__(256) void gemm_bt(const bf16* __restrict__ A,
                                               const bf16* __restrict__ W,
                                               const float* __restrict__ bias,
                                               bf16* __restrict__ outb,
                                               float* __restrict__ outf,
                                               const float* __restrict__ resid,
                                               const float* __restrict__ gamma,
                                               int N, int K) {
    __shared__ __attribute__((aligned(16))) bf16 As[128][72];
    __shared__ __attribute__((aligned(16))) bf16 Bs[128][72];
    int tid = threadIdx.x;
    int wave = tid >> 6, lane = tid & 63;
    int l15 = lane & 15, quad = lane >> 4;
    int bm = blockIdx.y * 128, bn = blockIdx.x * 128;
    int wm = (wave & 1) * 64, wn = (wave >> 1) * 64;
    f32x4 acc[4][4] = {};

    for (int k0 = 0; k0 < K; k0 += 64) {
#pragma unroll
        for (int i = 0; i < 4; i++) {
            int chunk = tid + i * 256;       // 1024 chunks of 8 bf16 per 128x64 tile
            int row = chunk >> 3, cc = chunk & 7;
            *(bf16x8*)&As[row][cc * 8] =
                *(const bf16x8*)(A + (size_t)(bm + row) * K + k0 + cc * 8);
            *(bf16x8*)&Bs[row][cc * 8] =
                *(const bf16x8*)(W + (size_t)(bn + row) * K + k0 + cc * 8);
        }
        __syncthreads();
#pragma unroll
        for (int ks = 0; ks < 2; ks++) {
            bf16x8 af[4], bfg[4];
#pragma unroll
            for (int mt = 0; mt < 4; mt++)
                af[mt] = *(const bf16x8*)&As[wm + mt * 16 + l15][ks * 32 + quad * 8];
#pragma unroll
            for (int nt = 0; nt < 4; nt++)
                bfg[nt] = *(const bf16x8*)&Bs[wn + nt * 16 + l15][ks * 32 + quad * 8];
#pragma unroll
            for (int mt = 0; mt < 4; mt++)
#pragma unroll
                for (int nt = 0; nt < 4; nt++)
                    acc[mt][nt] = __builtin_amdgcn_mfma_f32_16x16x32_bf16(
                        af[mt], bfg[nt], acc[mt][nt], 0, 0, 0);
        }
        __syncthreads();
    }

#pragma unroll
    for (int mt = 0; mt < 4; mt++) {
#pragma unroll
        for (int nt = 0; nt < 4; nt++) {
#pragma unroll
            for (int r = 0; r < 4; r++) {
                int row = bm + wm + mt * 16 + quad * 4 + r;
                int col = bn + wn + nt * 16 + l15;
                float v = acc[mt][nt][r];
                if (EPI >= 1) v += bias[col];
                if (EPI == 2) v = 0.5f * v * (1.f + erff(v * 0.70710678118654752f));
                if (EPI == 3) {
                    size_t idx = (size_t)row * N + col;
                    outf[idx] = resid[idx] + v * gamma[col];
                } else {
                    outb[(size_t)row * N + col] = (bf16)v;
                }
            }
        }
    }
}

// ---------------- flash attention: 64 Q rows per block, 4 waves x 16 rows ----
__global__ __launch_bounds__(256) void attn_kernel(const bf16* __restrict__ qkv,
                                                   bf16* __restrict__ o) {
    __shared__ __attribute__((aligned(16))) bf16 Ks[64][72];
    __shared__ __attribute__((aligned(16))) bf16 Vts[64][72];
    __shared__ __attribute__((aligned(16))) bf16 Ps[4][16][72];
    int tid = threadIdx.x, wave = tid >> 6, lane = tid & 63;
    int l15 = lane & 15, quad = lane >> 4;
    int qchunk = blockIdx.x;  // 0..31
    int bh = blockIdx.y;      // 0..47
    int b = bh / HEADS, h = bh - b * HEADS;
    int qbase = qchunk * 64 + wave * 16;
    const size_t rstr = 3 * DIM;  // 1152
    const bf16* base = qkv + (size_t)b * SEQ * rstr;

    bf16x8 aq[2];
#pragma unroll
    for (int ks = 0; ks < 2; ks++)
        aq[ks] = *(const bf16x8*)(base + (size_t)(qbase + l15) * rstr + h * 64 + ks * 32 + quad * 8);

    float mrow[4], lrow[4];
    f32x4 oacc[4] = {};
#pragma unroll
    for (int r = 0; r < 4; r++) { mrow[r] = -1e30f; lrow[r] = 0.f; }
    const float sc = 0.125f * 1.44269504088896340736f;  // head_dim^-0.5 * log2(e)

    for (int kt = 0; kt < SEQ / 64; kt++) {
        int kb = kt * 64;
#pragma unroll
        for (int i = 0; i < 2; i++) {
            int chunk = tid + i * 256;  // 512 chunks of 8 bf16 per 64x64 tile
            int row = chunk >> 3, cc = chunk & 7;
            *(bf16x8*)&Ks[row][cc * 8] =
                *(const bf16x8*)(base + (size_t)(kb + row) * rstr + DIM + h * 64 + cc * 8);
            bf16x8 vv = *(const bf16x8*)(base + (size_t)(kb + row) * rstr + 2 * DIM + h * 64 + cc * 8);
#pragma unroll
            for (int j = 0; j < 8; j++) Vts[cc * 8 + j][row] = vv[j];
        }
        __syncthreads();

        // S = Q K^T  (16 x 64 per wave)
        f32x4 s[4] = {};
#pragma unroll
        for (int ks = 0; ks < 2; ks++) {
#pragma unroll
            for (int nt = 0; nt < 4; nt++) {
                bf16x8 bk = *(const bf16x8*)&Ks[nt * 16 + l15][ks * 32 + quad * 8];
                s[nt] = __builtin_amdgcn_mfma_f32_16x16x32_bf16(aq[ks], bk, s[nt], 0, 0, 0);
            }
        }
#pragma unroll
        for (int nt = 0; nt < 4; nt++) s[nt] *= sc;

        // online softmax (exp2 domain); row r lives in lanes with same quad
#pragma unroll
        for (int r = 0; r < 4; r++) {
            float mx = fmaxf(fmaxf(s[0][r], s[1][r]), fmaxf(s[2][r], s[3][r]));
#pragma unroll
            for (int msk = 1; msk < 16; msk <<= 1) mx = fmaxf(mx, __shfl_xor(mx, msk, 64));
            float mnew = fmaxf(mrow[r], mx);
            float al = exp2f(mrow[r] - mnew);
            float rs = 0.f;
#pragma unroll
            for (int nt = 0; nt < 4; nt++) {
                float p = exp2f(s[nt][r] - mnew);
                s[nt][r] = p;
                rs += p;
            }
#pragma unroll
            for (int msk = 1; msk < 16; msk <<= 1) rs += __shfl_xor(rs, msk, 64);
            lrow[r] = lrow[r] * al + rs;
            mrow[r] = mnew;
#pragma unroll
            for (int dt = 0; dt < 4; dt++) oacc[dt][r] *= al;
        }

        // P: C-layout -> LDS -> A-layout
#pragma unroll
        for (int r = 0; r < 4; r++)
#pragma unroll
            for (int nt = 0; nt < 4; nt++)
                Ps[wave][quad * 4 + r][nt * 16 + l15] = (bf16)s[nt][r];
        __syncthreads();

        // O += P @ V
#pragma unroll
        for (int ks = 0; ks < 2; ks++) {
            bf16x8 ap = *(const bf16x8*)&Ps[wave][l15][ks * 32 + quad * 8];
#pragma unroll
            for (int dt = 0; dt < 4; dt++) {
                bf16x8 bv = *(const bf16x8*)&Vts[dt * 16 + l15][ks * 32 + quad * 8];
                oacc[dt] = __builtin_amdgcn_mfma_f32_16x16x32_bf16(ap, bv, oacc[dt], 0, 0, 0);
            }
        }
        __syncthreads();
    }

#pragma unroll
    for (int r = 0; r < 4; r++) {
        float inv = 1.f / lrow[r];
        int qrow = qbase + quad * 4 + r;
        bf16* orow = o + ((size_t)(b * SEQ + qrow)) * DIM + h * 64;
#pragma unroll
        for (int dt = 0; dt < 4; dt++) orow[dt * 16 + l15] = (bf16)(oacc[dt][r] * inv);
    }
}

// ---------------- orchestration ----------------------------------------------
extern "C" void kernel_launch(void* const* d_in, const int* in_sizes, int n_in,
                              void* d_out, int out_size, void* d_ws, size_t ws_size,
                              hipStream_t stream) {
    const float* x      = (const float*)d_in[0];
    const float* qkv_w  = (const float*)d_in[1];
    const float* qkv_b  = (const float*)d_in[2];
    const float* proj_w = (const float*)d_in[3];
    const float* proj_b = (const float*)d_in[4];
    const float* fc1_w  = (const float*)d_in[5];
    const float* fc1_b  = (const float*)d_in[6];
    const float* eye1_w = (const float*)d_in[7];
    const float* eye2_w = (const float*)d_in[8];
    const float* fc2_w  = (const float*)d_in[9];
    const float* fc2_b  = (const float*)d_in[10];
    const float* n1w    = (const float*)d_in[11];
    const float* n1b    = (const float*)d_in[12];
    const float* n2w    = (const float*)d_in[13];
    const float* n2b    = (const float*)d_in[14];
    const float* ls1    = (const float*)d_in[15];
    const float* ls2    = (const float*)d_in[16];
    float* out = (float*)d_out;

    char* w = (char*)d_ws;
    size_t off = 0;
    bf16* wcat = (bf16*)(w + off); off += (size_t)NW_TOTAL * 2;
    bf16* wqkv  = wcat;
    bf16* wproj = wqkv + NW_QKV;
    bf16* wfc1  = wproj + NW_PROJ;
    bf16* weye1 = wfc1 + NW_FC1;
    bf16* weye2 = weye1 + NW_EYE;
    bf16* wfc2  = weye2 + NW_EYE;
    bf16* hbuf  = (bf16*)(w + off); off += (size_t)TOKENS * DIM * 2;       // LN out (reused for LN2)
    bf16* qkvb  = (bf16*)(w + off); off += (size_t)TOKENS * 3 * DIM * 2;   // QKV
    bf16* obuf  = (bf16*)(w + off); off += (size_t)TOKENS * DIM * 2;       // attn out
    bf16* abuf  = (bf16*)(w + off); off += (size_t)TOKENS * HIDDEN * 2;    // fc1/gelu out (reused for u)
    bf16* tbuf  = (bf16*)(w + off); off += (size_t)TOKENS * HIDDEN * 2;    // eye1 out
    float* x1   = (float*)(w + off); off += (size_t)TOKENS * DIM * 4;      // residual spine

    convert_weights<<<4096, 256, 0, stream>>>(qkv_w, proj_w, fc1_w, eye1_w, eye2_w, fc2_w, wcat);

    ln_kernel<<<TOKENS / 4, 256, 0, stream>>>(x, n1w, n1b, hbuf);

    gemm_bt<1><<<dim3(1152 / 128, TOKENS / 128), 256, 0, stream>>>(
        hbuf, wqkv, qkv_b, qkvb, nullptr, nullptr, nullptr, 1152, 384);

    attn_kernel<<<dim3(SEQ / 64, BATCH * HEADS), 256, 0, stream>>>(qkvb, obuf);

    gemm_bt<3><<<dim3(384 / 128, TOKENS / 128), 256, 0, stream>>>(
        obuf, wproj, proj_b, nullptr, x1, x, ls1, 384, 384);

    ln_kernel<<<TOKENS / 4, 256, 0, stream>>>(x1, n2w, n2b, hbuf);

    gemm_bt<2><<<dim3(1536 / 128, TOKENS / 128), 256, 0, stream>>>(
        hbuf, wfc1, fc1_b, abuf, nullptr, nullptr, nullptr, 1536, 384);

    gemm_bt<0><<<dim3(1536 / 128, TOKENS / 128), 256, 0, stream>>>(
        abuf, weye1, nullptr, tbuf, nullptr, nullptr, nullptr, 1536, 1536);

    gemm_bt<0><<<dim3(1536 / 128, TOKENS / 128), 256, 0, stream>>>(
        tbuf, weye2, nullptr, abuf, nullptr, nullptr, nullptr, 1536, 1536);

    gemm_bt<3><<<dim3(384 / 128, TOKENS / 128), 256, 0, stream>>>(
        abuf, wfc2, fc2_b, nullptr, out, x1, ls2, 384, 1536);
}

// Round 2
// 565.134 us; speedup vs baseline: 1.2675x; 1.2675x over previous
//
#include <hip/hip_runtime.h>
#include <math.h>

#define DIM 384
#define HEADS 6
#define HEAD_DIM 64
#define HIDDEN 1536
#define BATCH 8
#define SEQ 2048
#define TOKENS (BATCH * SEQ)

typedef __bf16 bf16;
typedef __bf16 bf16x8 __attribute__((ext_vector_type(8)));
typedef __bf16 bf16x4 __attribute__((ext_vector_type(4)));
typedef float f32x4 __attribute__((ext_vector_type(4)));

#define GLOAD_LDS(gp, lp)                                                      \
    __builtin_amdgcn_global_load_lds(                                          \
        (const __attribute__((address_space(1))) void*)(gp),                   \
        (__attribute__((address_space(3))) void*)(lp), 16, 0, 0)

// ---------------- weight conversion (fp32 -> bf16) ---------------------------
#define NW_QKV  (1152 * 384)
#define NW_PROJ (384 * 384)
#define NW_FC1  (1536 * 384)
#define NW_EYE  (1536 * 1536)
#define NW_FC2  (384 * 1536)
#define NW_TOTAL (NW_QKV + NW_PROJ + NW_FC1 + 2 * NW_EYE + NW_FC2)

__global__ void convert_weights(const float* __restrict__ qkv, const float* __restrict__ proj,
                                const float* __restrict__ fc1, const float* __restrict__ e1,
                                const float* __restrict__ e2, const float* __restrict__ fc2,
                                bf16* __restrict__ dst) {
    int i = blockIdx.x * 256 + threadIdx.x;
    int stride = gridDim.x * 256;
    for (; i < NW_TOTAL; i += stride) {
        int j = i;
        float v;
        if (j < NW_QKV) v = qkv[j];
        else if ((j -= NW_QKV) < NW_PROJ) v = proj[j];
        else if ((j -= NW_PROJ) < NW_FC1) v = fc1[j];
        else if ((j -= NW_FC1) < NW_EYE) v = e1[j];
        else if ((j -= NW_EYE) < NW_EYE) v = e2[j];
        else v = fc2[j - NW_EYE];
        dst[i] = (bf16)v;
    }
}

// ---------------- LayerNorm: fp32 in -> bf16 out, one wave per token ---------
__global__ __launch_bounds__(256) void ln_kernel(const float* __restrict__ x,
                                                 const float* __restrict__ w,
                                                 const float* __restrict__ b,
                                                 bf16* __restrict__ out) {
    int wave = threadIdx.x >> 6;
    int lane = threadIdx.x & 63;
    int t = blockIdx.x * 4 + wave;
    const float* xr = x + (size_t)t * DIM;
    float v[6];
    float s = 0.f;
#pragma unroll
    for (int i = 0; i < 6; i++) { v[i] = xr[lane + 64 * i]; s += v[i]; }
#pragma unroll
    for (int m = 1; m < 64; m <<= 1) s += __shfl_xor(s, m, 64);
    float mu = s * (1.f / DIM);
    float q = 0.f;
#pragma unroll
    for (int i = 0; i < 6; i++) { float d = v[i] - mu; q += d * d; }
#pragma unroll
    for (int m = 1; m < 64; m <<= 1) q += __shfl_xor(q, m, 64);
    float rstd = rsqrtf(q * (1.f / DIM) + 1e-5f);
    bf16* orow = out + (size_t)t * DIM;
#pragma unroll
    for (int i = 0; i < 6; i++) {
        int c = lane + 64 * i;
        orow[c] = (bf16)((v[i] - mu) * rstd * w[c] + b[c]);
    }
}

// ---------------- GEMM: C[M,N] = A[M,K] @ W[N,K]^T (+ epilogue) --------------
// EPI 0: plain -> bf16   EPI 1: +bias -> bf16   EPI 2: +bias,GELU -> bf16
// EPI 3: +bias, out_f32 = resid + v*gamma
// QS: multiply columns [0,384) by 0.125*log2(e) (pre-scale Q for attention)
template <int EPI, bool QS>
__global__ __launch_bounds__(256) void gemm_bt(const bf16* __restrict__ A,
                                               const bf16* __restrict__ W,
                                               const float* __restrict__ bias,
                                               bf16* __restrict__ outb,
                                               float* __restrict__ outf,
                                               const float* __restrict__ resid,
                                               const float* __restrict__ gamma,
                                               int N, int K) {
    // unpadded, XOR-swizzled: element row r, colgroup g (8 bf16) lives at
    // slot 8*r + (g ^ (r&7)); global_load_lds fills slots in lane order.
    __shared__ __attribute__((aligned(16))) bf16 As[128 * 64];
    __shared__ __attribute__((aligned(16))) bf16 Bs[128 * 64];
    int tid = threadIdx.x;
    int wave = tid >> 6, lane = tid & 63;
    int l15 = lane & 15, quad = lane >> 4;
    int bm = blockIdx.y * 128, bn = blockIdx.x * 128;
    int wm = (wave & 1) * 64, wn = (wave >> 1) * 64;
    f32x4 acc[4][4] = {};

    for (int k0 = 0; k0 < K; k0 += 64) {
#pragma unroll
        for (int i = 0; i < 4; i++) {
            int slot = i * 256 + tid;
            int rr = slot >> 3;
            int gg = (slot & 7) ^ (rr & 7);
            GLOAD_LDS(A + (size_t)(bm + rr) * K + k0 + gg * 8,
                      (char*)As + (i * 256 + wave * 64) * 16);
            GLOAD_LDS(W + (size_t)(bn + rr) * K + k0 + gg * 8,
                      (char*)Bs + (i * 256 + wave * 64) * 16);
        }
        __syncthreads();
#pragma unroll
        for (int ks = 0; ks < 2; ks++) {
            bf16x8 af[4], bfg[4];
#pragma unroll
            for (int mt = 0; mt < 4; mt++) {
                int rA = wm + mt * 16 + l15;
                af[mt] = *(const bf16x8*)((char*)As +
                         16 * (8 * rA + ((4 * ks + quad) ^ (rA & 7))));
            }
#pragma unroll
            for (int nt = 0; nt < 4; nt++) {
                int rB = wn + nt * 16 + l15;
                bfg[nt] = *(const bf16x8*)((char*)Bs +
                          16 * (8 * rB + ((4 * ks + quad) ^ (rB & 7))));
            }
#pragma unroll
            for (int mt = 0; mt < 4; mt++)
#pragma unroll
                for (int nt = 0; nt < 4; nt++)
                    acc[mt][nt] = __builtin_amdgcn_mfma_f32_16x16x32_bf16(
                        af[mt], bfg[nt], acc[mt][nt], 0, 0, 0);
        }
        __syncthreads();
    }

#pragma unroll
    for (int mt = 0; mt < 4; mt++) {
#pragma unroll
        for (int nt = 0; nt < 4; nt++) {
#pragma unroll
            for (int r = 0; r < 4; r++) {
                int row = bm + wm + mt * 16 + quad * 4 + r;
                int col = bn + wn + nt * 16 + l15;
                float v = acc[mt][nt][r];
                if (EPI >= 1) v += bias[col];
                if (EPI == 2) v = 0.5f * v * (1.f + erff(v * 0.70710678118654752f));
                if (QS && col < 384) v *= 0.180336880f;  // 0.125 * log2(e)
                if (EPI == 3) {
                    size_t idx = (size_t)row * N + col;
                    outf[idx] = resid[idx] + v * gamma[col];
                } else {
                    outb[(size_t)row * N + col] = (bf16)v;
                }
            }
        }
    }
}

// ---------------- flash attention, S^T formulation, no-max softmax -----------
// 64 Q rows/block, 4 waves x 16 rows. Q pre-scaled by 0.125*log2(e).
__global__ __launch_bounds__(256) void attn_kernel(const bf16* __restrict__ qkv,
                                                   bf16* __restrict__ o) {
    __shared__ __attribute__((aligned(16))) bf16 Ks[64 * 64];     // swizzled slots
    __shared__ __attribute__((aligned(16))) bf16 Vts[64][72];     // V^T, xor-swizzled cols
    __shared__ __attribute__((aligned(16))) bf16 Ps[4][16][72];   // per-wave P
    int tid = threadIdx.x, wave = tid >> 6, lane = tid & 63;
    int l15 = lane & 15, quad = lane >> 4;
    int bh = blockIdx.y;
    int b = bh / HEADS, h = bh - b * HEADS;
    int qr0 = blockIdx.x * 64 + wave * 16;
    const size_t rstr = 3 * DIM;  // 1152
    const bf16* base = qkv + (size_t)b * SEQ * rstr;

    // Q fragment (B-operand): row n=l15 holds Q[qr0+l15][k = 32ks+8q+j]
    bf16x8 aq[2];
#pragma unroll
    for (int ks = 0; ks < 2; ks++)
        aq[ks] = *(const bf16x8*)(base + (size_t)(qr0 + l15) * rstr + h * 64 + ks * 32 + quad * 8);

    f32x4 oacc[4] = {};
    float lsum = 0.f;

    for (int kt = 0; kt < SEQ / 64; kt++) {
        int kb = kt * 64;
        // K stage: global_load_lds, swizzled chunk assignment
#pragma unroll
        for (int i = 0; i < 2; i++) {
            int slot = i * 256 + tid;
            int rr = slot >> 3;
            int gg = (slot & 7) ^ (rr & 7);
            GLOAD_LDS(base + (size_t)(kb + rr) * rstr + DIM + h * 64 + gg * 8,
                      (char*)Ks + (i * 256 + wave * 64) * 16);
        }
        // V stage: transpose with xor-swizzled column to kill bank conflicts
#pragma unroll
        for (int i = 0; i < 2; i++) {
            int chunk = tid + i * 256;
            int row = chunk >> 3, cc = chunk & 7;
            bf16x8 vv = *(const bf16x8*)(base + (size_t)(kb + row) * rstr + 2 * DIM + h * 64 + cc * 8);
#pragma unroll
            for (int j = 0; j < 8; j++) Vts[cc * 8 + j][row ^ (cc * 8)] = vv[j];
        }
        __syncthreads();

        // S^T = K Q^T : lane(q,l) gets S^T[16nt+4q+r][l15] = P-row m=l15
        f32x4 s[4] = {};
#pragma unroll
        for (int ks = 0; ks < 2; ks++) {
#pragma unroll
            for (int nt = 0; nt < 4; nt++) {
                int rK = nt * 16 + l15;
                bf16x8 ak = *(const bf16x8*)((char*)Ks +
                            16 * (8 * rK + ((4 * ks + quad) ^ (rK & 7))));
                s[nt] = __builtin_amdgcn_mfma_f32_16x16x32_bf16(ak, aq[ks], s[nt], 0, 0, 0);
            }
        }

        // no-max softmax: P = exp2(S~), per-lane partial row sum
#pragma unroll
        for (int nt = 0; nt < 4; nt++) {
#pragma unroll
            for (int r = 0; r < 4; r++) {
                float p = exp2f(s[nt][r]);
                s[nt][r] = p;
                lsum += p;
            }
        }

        // P: pack 4 consecutive n per lane -> single b64 write (wave-private)
#pragma unroll
        for (int nt = 0; nt < 4; nt++) {
            bf16x4 pk;
#pragma unroll
            for (int r = 0; r < 4; r++) pk[r] = (bf16)s[nt][r];
            *(bf16x4*)&Ps[wave][l15][nt * 16 + quad * 4] = pk;
        }

        // O += P V (A = P from LDS, B = V^T rows from Vts)
#pragma unroll
        for (int ks = 0; ks < 2; ks++) {
            bf16x8 ap = *(const bf16x8*)&Ps[wave][l15][ks * 32 + quad * 8];
#pragma unroll
            for (int dt = 0; dt < 4; dt++) {
                int d = dt * 16 + l15;
                int colsw = (32 * ks + 8 * quad) ^ ((d >> 3) * 8);
                bf16x8 bv = *(const bf16x8*)((char*)&Vts[0][0] + ((size_t)d * 72 + colsw) * 2);
                oacc[dt] = __builtin_amdgcn_mfma_f32_16x16x32_bf16(ap, bv, oacc[dt], 0, 0, 0);
            }
        }
        __syncthreads();
    }

    // finalize: reduce row sums across quads (rows live at l15)
    lsum += __shfl_xor(lsum, 16, 64);
    lsum += __shfl_xor(lsum, 32, 64);
#pragma unroll
    for (int r = 0; r < 4; r++) {
        float lt = __shfl(lsum, 4 * quad + r, 64);  // sum for row m = 4q+r
        float inv = 1.f / lt;
        int qrow = qr0 + 4 * quad + r;
        bf16* orow = o + ((size_t)(b * SEQ + qrow)) * DIM + h * 64;
#pragma unroll
        for (int dt = 0; dt < 4; dt++) orow[dt * 16 + l15] = (bf16)(oacc[dt][r] * inv);
    }
}

// ---------------- orchestration ----------------------------------------------
extern "C" void kernel_launch(void* const* d_in, const int* in_sizes, int n_in,
                              void* d_out, int out_size, void* d_ws, size_t ws_size,
                              hipStream_t stream) {
    const float* x      = (const float*)d_in[0];
    const float* qkv_w  = (const float*)d_in[1];
    const float* qkv_b  = (const float*)d_in[2];
    const float* proj_w = (const float*)d_in[3];
    const float* proj_b = (const float*)d_in[4];
    const float* fc1_w  = (const float*)d_in[5];
    const float* fc1_b  = (const float*)d_in[6];
    const float* eye1_w = (const float*)d_in[7];
    const float* eye2_w = (const float*)d_in[8];
    const float* fc2_w  = (const float*)d_in[9];
    const float* fc2_b  = (const float*)d_in[10];
    const float* n1w    = (const float*)d_in[11];
    const float* n1b    = (const float*)d_in[12];
    const float* n2w    = (const float*)d_in[13];
    const float* n2b    = (const float*)d_in[14];
    const float* ls1    = (const float*)d_in[15];
    const float* ls2    = (const float*)d_in[16];
    float* out = (float*)d_out;

    char* w = (char*)d_ws;
    size_t off = 0;
    bf16* wcat = (bf16*)(w + off); off += (size_t)NW_TOTAL * 2;
    bf16* wqkv  = wcat;
    bf16* wproj = wqkv + NW_QKV;
    bf16* wfc1  = wproj + NW_PROJ;
    bf16* weye1 = wfc1 + NW_FC1;
    bf16* weye2 = weye1 + NW_EYE;
    bf16* wfc2  = weye2 + NW_EYE;
    bf16* hbuf  = (bf16*)(w + off); off += (size_t)TOKENS * DIM * 2;
    bf16* qkvb  = (bf16*)(w + off); off += (size_t)TOKENS * 3 * DIM * 2;
    bf16* obuf  = (bf16*)(w + off); off += (size_t)TOKENS * DIM * 2;
    bf16* abuf  = (bf16*)(w + off); off += (size_t)TOKENS * HIDDEN * 2;
    bf16* tbuf  = (bf16*)(w + off); off += (size_t)TOKENS * HIDDEN * 2;
    float* x1   = (float*)(w + off); off += (size_t)TOKENS * DIM * 4;

    convert_weights<<<4096, 256, 0, stream>>>(qkv_w, proj_w, fc1_w, eye1_w, eye2_w, fc2_w, wcat);

    ln_kernel<<<TOKENS / 4, 256, 0, stream>>>(x, n1w, n1b, hbuf);

    gemm_bt<1, true><<<dim3(1152 / 128, TOKENS / 128), 256, 0, stream>>>(
        hbuf, wqkv, qkv_b, qkvb, nullptr, nullptr, nullptr, 1152, 384);

    attn_kernel<<<dim3(SEQ / 64, BATCH * HEADS), 256, 0, stream>>>(qkvb, obuf);

    gemm_bt<3, false><<<dim3(384 / 128, TOKENS / 128), 256, 0, stream>>>(
        obuf, wproj, proj_b, nullptr, x1, x, ls1, 384, 384);

    ln_kernel<<<TOKENS / 4, 256, 0, stream>>>(x1, n2w, n2b, hbuf);

    gemm_bt<2, false><<<dim3(1536 / 128, TOKENS / 128), 256, 0, stream>>>(
        hbuf, wfc1, fc1_b, abuf, nullptr, nullptr, nullptr, 1536, 384);

    gemm_bt<0, false><<<dim3(1536 / 128, TOKENS / 128), 256, 0, stream>>>(
        abuf, weye1, nullptr, tbuf, nullptr, nullptr, nullptr, 1536, 1536);

    gemm_bt<0, false><<<dim3(1536 / 128, TOKENS / 128), 256, 0, stream>>>(
        tbuf, weye2, nullptr, abuf, nullptr, nullptr, nullptr, 1536, 1536);

    gemm_bt<3, false><<<dim3(384 / 128, TOKENS / 128), 256, 0, stream>>>(
        abuf, wfc2, fc2_b, nullptr, out, x1, ls2, 384, 1536);
}

// Round 3
// 525.316 us; speedup vs baseline: 1.3636x; 1.0758x over previous
//
#include <hip/hip_runtime.h>
#include <math.h>

#define DIM 384
#define HEADS 6
#define HEAD_DIM 64
#define HIDDEN 1536
#define BATCH 8
#define SEQ 2048
#define TOKENS (BATCH * SEQ)

typedef __bf16 bf16;
typedef __bf16 bf16x8 __attribute__((ext_vector_type(8)));
typedef __bf16 bf16x4 __attribute__((ext_vector_type(4)));
typedef float f32x4 __attribute__((ext_vector_type(4)));

#define GLOAD_LDS(gp, lp)                                                      \
    __builtin_amdgcn_global_load_lds(                                          \
        (const __attribute__((address_space(1))) void*)(gp),                   \
        (__attribute__((address_space(3))) void*)(lp), 16, 0, 0)

// ---------------- weight conversion (fp32 -> bf16, float4 vectorized) --------
#define NW_QKV  (1152 * 384)
#define NW_PROJ (384 * 384)
#define NW_FC1  (1536 * 384)
#define NW_EYE  (1536 * 1536)
#define NW_FC2  (384 * 1536)
#define NW_TOTAL (NW_QKV + NW_PROJ + NW_FC1 + 2 * NW_EYE + NW_FC2)

__global__ void convert_weights(const float* __restrict__ qkv, const float* __restrict__ proj,
                                const float* __restrict__ fc1, const float* __restrict__ e1,
                                const float* __restrict__ e2, const float* __restrict__ fc2,
                                bf16* __restrict__ dst) {
    int q4 = blockIdx.x * 256 + threadIdx.x;
    int stride = gridDim.x * 256;
    for (; q4 < NW_TOTAL / 4; q4 += stride) {
        int i = q4 * 4;
        int j = i;
        const float* src;
        if (j < NW_QKV) src = qkv;
        else if ((j -= NW_QKV) < NW_PROJ) src = proj;
        else if ((j -= NW_PROJ) < NW_FC1) src = fc1;
        else if ((j -= NW_FC1) < NW_EYE) src = e1;
        else if ((j -= NW_EYE) < NW_EYE) src = e2;
        else { j -= NW_EYE; src = fc2; }
        float4 v = *(const float4*)(src + j);
        bf16x4 o; o[0] = (bf16)v.x; o[1] = (bf16)v.y; o[2] = (bf16)v.z; o[3] = (bf16)v.w;
        *(bf16x4*)(dst + i) = o;
    }
}

// ---------------- LayerNorm: fp32 in -> bf16 out, one wave per token ---------
__global__ __launch_bounds__(256) void ln_kernel(const float* __restrict__ x,
                                                 const float* __restrict__ w,
                                                 const float* __restrict__ b,
                                                 bf16* __restrict__ out) {
    int wave = threadIdx.x >> 6;
    int lane = threadIdx.x & 63;
    int t = blockIdx.x * 4 + wave;
    const float* xr = x + (size_t)t * DIM;
    float v[6];
    float s = 0.f;
#pragma unroll
    for (int i = 0; i < 6; i++) { v[i] = xr[lane + 64 * i]; s += v[i]; }
#pragma unroll
    for (int m = 1; m < 64; m <<= 1) s += __shfl_xor(s, m, 64);
    float mu = s * (1.f / DIM);
    float q = 0.f;
#pragma unroll
    for (int i = 0; i < 6; i++) { float d = v[i] - mu; q += d * d; }
#pragma unroll
    for (int m = 1; m < 64; m <<= 1) q += __shfl_xor(q, m, 64);
    float rstd = rsqrtf(q * (1.f / DIM) + 1e-5f);
    bf16* orow = out + (size_t)t * DIM;
#pragma unroll
    for (int i = 0; i < 6; i++) {
        int c = lane + 64 * i;
        orow[c] = (bf16)((v[i] - mu) * rstd * w[c] + b[c]);
    }
}

// ---------------- GEMM: C[M,N] = A[M,K] @ W[N,K]^T (+ epilogue) --------------
// EPI 0: plain -> bf16   EPI 1: +bias -> bf16   EPI 2: +bias,GELU -> bf16
// EPI 3: +bias, out_f32 = resid + v*gamma
// EPI 4: qkv special: +bias; Q cols scaled -> qkvb; V cols -> vtb transposed
template <int EPI>
__global__ __launch_bounds__(256) void gemm_bt(const bf16* __restrict__ A,
                                               const bf16* __restrict__ W,
                                               const float* __restrict__ bias,
                                               bf16* __restrict__ outb,
                                               float* __restrict__ outf,
                                               const float* __restrict__ resid,
                                               const float* __restrict__ gamma,
                                               bf16* __restrict__ vtb,
                                               int N, int K) {
    // unpadded, XOR-swizzled: row r, colgroup g (8 bf16) -> slot 8*r + (g^(r&7))
    __shared__ __attribute__((aligned(16))) bf16 As[128 * 64];
    __shared__ __attribute__((aligned(16))) bf16 Bs[128 * 64];
    int tid = threadIdx.x;
    int wave = tid >> 6, lane = tid & 63;
    int l15 = lane & 15, quad = lane >> 4;
    int bm = blockIdx.y * 128, bn = blockIdx.x * 128;
    int wm = (wave & 1) * 64, wn = (wave >> 1) * 64;
    f32x4 acc[4][4] = {};

    for (int k0 = 0; k0 < K; k0 += 64) {
#pragma unroll
        for (int i = 0; i < 4; i++) {
            int slot = i * 256 + tid;
            int rr = slot >> 3;
            int gg = (slot & 7) ^ (rr & 7);
            GLOAD_LDS(A + (size_t)(bm + rr) * K + k0 + gg * 8,
                      (char*)As + (i * 256 + wave * 64) * 16);
            GLOAD_LDS(W + (size_t)(bn + rr) * K + k0 + gg * 8,
                      (char*)Bs + (i * 256 + wave * 64) * 16);
        }
        __syncthreads();
#pragma unroll
        for (int ks = 0; ks < 2; ks++) {
            bf16x8 af[4], bfg[4];
#pragma unroll
            for (int mt = 0; mt < 4; mt++) {
                int rA = wm + mt * 16 + l15;
                af[mt] = *(const bf16x8*)((char*)As +
                         16 * (8 * rA + ((4 * ks + quad) ^ (rA & 7))));
            }
#pragma unroll
            for (int nt = 0; nt < 4; nt++) {
                int rB = wn + nt * 16 + l15;
                bfg[nt] = *(const bf16x8*)((char*)Bs +
                          16 * (8 * rB + ((4 * ks + quad) ^ (rB & 7))));
            }
#pragma unroll
            for (int mt = 0; mt < 4; mt++)
#pragma unroll
                for (int nt = 0; nt < 4; nt++)
                    acc[mt][nt] = __builtin_amdgcn_mfma_f32_16x16x32_bf16(
                        af[mt], bfg[nt], acc[mt][nt], 0, 0, 0);
        }
        __syncthreads();
    }

#pragma unroll
    for (int mt = 0; mt < 4; mt++) {
#pragma unroll
        for (int nt = 0; nt < 4; nt++) {
            int col = bn + wn + nt * 16 + l15;
            int row0 = bm + wm + mt * 16 + quad * 4;
            float v[4];
#pragma unroll
            for (int r = 0; r < 4; r++) {
                v[r] = acc[mt][nt][r];
                if (EPI >= 1) v[r] += bias[col];
                if (EPI == 2) v[r] = 0.5f * v[r] * (1.f + erff(v[r] * 0.70710678118654752f));
            }
            if (EPI == 3) {
#pragma unroll
                for (int r = 0; r < 4; r++) {
                    size_t idx = (size_t)(row0 + r) * N + col;
                    outf[idx] = resid[idx] + v[r] * gamma[col];
                }
            } else if (EPI == 4) {
                if (col < 768) {  // wave-uniform per nt (boundary multiple of 16)
                    float sc = (col < 384) ? 0.180336880f : 1.f;  // 0.125*log2(e)
#pragma unroll
                    for (int r = 0; r < 4; r++)
                        outb[(size_t)(row0 + r) * N + col] = (bf16)(v[r] * sc);
                } else {
                    int hd = col - 768;             // head*64 + d
                    int b = row0 >> 11;             // token row / 2048
                    int n0 = row0 & 2047;
                    bf16x4 pk;
#pragma unroll
                    for (int r = 0; r < 4; r++) pk[r] = (bf16)v[r];
                    *(bf16x4*)(vtb + ((size_t)(b * 384 + hd) << 11) + n0) = pk;
                }
            } else {
#pragma unroll
                for (int r = 0; r < 4; r++)
                    outb[(size_t)(row0 + r) * N + col] = (bf16)v[r];
            }
        }
    }
}

// ---------------- flash attention: 128 Q rows/block, 4 waves x 32 rows -------
// Q pre-scaled by 0.125*log2(e); V^T pre-materialized in vtb[b][h][d][n].
__global__ __launch_bounds__(256) void attn_kernel(const bf16* __restrict__ qkv,
                                                   const bf16* __restrict__ vtb,
                                                   bf16* __restrict__ o) {
    __shared__ __attribute__((aligned(16))) bf16 Ks[64 * 64];   // swizzled slots
    __shared__ __attribute__((aligned(16))) bf16 Vts[64 * 64];  // V^T tile, swizzled
    __shared__ __attribute__((aligned(16))) bf16 Ps[4][32][72]; // per-wave P
    int tid = threadIdx.x, wave = tid >> 6, lane = tid & 63;
    int l15 = lane & 15, quad = lane >> 4;
    int bh = blockIdx.y;
    int b = bh / HEADS, h = bh - b * HEADS;
    int qr0 = blockIdx.x * 128 + wave * 32;
    const size_t rstr = 3 * DIM;  // 1152
    const bf16* base = qkv + (size_t)b * SEQ * rstr;
    const bf16* vbase = vtb + ((size_t)bh << 17);  // bh*64*2048

    // Q fragments (B-operand): lane holds Q[qr0+qt*16+l15][32ks+8q+j]
    bf16x8 aq[2][2];
#pragma unroll
    for (int qt = 0; qt < 2; qt++)
#pragma unroll
        for (int ks = 0; ks < 2; ks++)
            aq[qt][ks] = *(const bf16x8*)(base + (size_t)(qr0 + qt * 16 + l15) * rstr +
                                          h * 64 + ks * 32 + quad * 8);

    f32x4 oacc[2][4] = {};
    float lsum[2] = {0.f, 0.f};

    for (int kt = 0; kt < SEQ / 64; kt++) {
        int kb = kt * 64;
#pragma unroll
        for (int i = 0; i < 2; i++) {
            int slot = i * 256 + tid;
            int rr = slot >> 3;
            int gg = (slot & 7) ^ (rr & 7);
            GLOAD_LDS(base + (size_t)(kb + rr) * rstr + DIM + h * 64 + gg * 8,
                      (char*)Ks + (i * 256 + wave * 64) * 16);
            GLOAD_LDS(vbase + ((size_t)rr << 11) + kb + gg * 8,
                      (char*)Vts + (i * 256 + wave * 64) * 16);
        }
        __syncthreads();

        // S^T = K Q^T : C-frag s[qt][nt], col=l15 -> q-row, row -> token
        f32x4 s[2][4] = {};
#pragma unroll
        for (int ks = 0; ks < 2; ks++) {
#pragma unroll
            for (int nt = 0; nt < 4; nt++) {
                int rK = nt * 16 + l15;
                bf16x8 ak = *(const bf16x8*)((char*)Ks +
                            16 * (8 * rK + ((4 * ks + quad) ^ (rK & 7))));
#pragma unroll
                for (int qt = 0; qt < 2; qt++)
                    s[qt][nt] = __builtin_amdgcn_mfma_f32_16x16x32_bf16(
                        ak, aq[qt][ks], s[qt][nt], 0, 0, 0);
            }
        }

        // no-max softmax: P = exp2(S~); pack 4 tokens -> b64 write (wave-private)
#pragma unroll
        for (int qt = 0; qt < 2; qt++)
#pragma unroll
            for (int nt = 0; nt < 4; nt++) {
                bf16x4 pk;
#pragma unroll
                for (int r = 0; r < 4; r++) {
                    float p = exp2f(s[qt][nt][r]);
                    lsum[qt] += p;
                    pk[r] = (bf16)p;
                }
                *(bf16x4*)&Ps[wave][qt * 16 + l15][nt * 16 + quad * 4] = pk;
            }

        // O += P V : A = P rows (q), B = V^T rows (d) from Vts
#pragma unroll
        for (int ks = 0; ks < 2; ks++) {
            bf16x8 ap[2];
#pragma unroll
            for (int qt = 0; qt < 2; qt++)
                ap[qt] = *(const bf16x8*)&Ps[wave][qt * 16 + l15][ks * 32 + quad * 8];
#pragma unroll
            for (int dt = 0; dt < 4; dt++) {
                int rV = dt * 16 + l15;
                bf16x8 bv = *(const bf16x8*)((char*)Vts +
                            16 * (8 * rV + ((4 * ks + quad) ^ (rV & 7))));
#pragma unroll
                for (int qt = 0; qt < 2; qt++)
                    oacc[qt][dt] = __builtin_amdgcn_mfma_f32_16x16x32_bf16(
                        ap[qt], bv, oacc[qt][dt], 0, 0, 0);
            }
        }
        __syncthreads();
    }

    // finalize: reduce row sums across quads (per-lane partials, rows at l15)
#pragma unroll
    for (int qt = 0; qt < 2; qt++) {
        lsum[qt] += __shfl_xor(lsum[qt], 16, 64);
        lsum[qt] += __shfl_xor(lsum[qt], 32, 64);
    }
#pragma unroll
    for (int qt = 0; qt < 2; qt++)
#pragma unroll
        for (int r = 0; r < 4; r++) {
            float lt = __shfl(lsum[qt], 4 * quad + r, 64);
            float inv = 1.f / lt;
            int qrow = qr0 + qt * 16 + quad * 4 + r;
            bf16* orow = o + ((size_t)(b * SEQ + qrow)) * DIM + h * 64;
#pragma unroll
            for (int dt = 0; dt < 4; dt++) orow[dt * 16 + l15] = (bf16)(oacc[qt][dt][r] * inv);
        }
}

// ---------------- orchestration ----------------------------------------------
extern "C" void kernel_launch(void* const* d_in, const int* in_sizes, int n_in,
                              void* d_out, int out_size, void* d_ws, size_t ws_size,
                              hipStream_t stream) {
    const float* x      = (const float*)d_in[0];
    const float* qkv_w  = (const float*)d_in[1];
    const float* qkv_b  = (const float*)d_in[2];
    const float* proj_w = (const float*)d_in[3];
    const float* proj_b = (const float*)d_in[4];
    const float* fc1_w  = (const float*)d_in[5];
    const float* fc1_b  = (const float*)d_in[6];
    const float* eye1_w = (const float*)d_in[7];
    const float* eye2_w = (const float*)d_in[8];
    const float* fc2_w  = (const float*)d_in[9];
    const float* fc2_b  = (const float*)d_in[10];
    const float* n1w    = (const float*)d_in[11];
    const float* n1b    = (const float*)d_in[12];
    const float* n2w    = (const float*)d_in[13];
    const float* n2b    = (const float*)d_in[14];
    const float* ls1    = (const float*)d_in[15];
    const float* ls2    = (const float*)d_in[16];
    float* out = (float*)d_out;

    char* w = (char*)d_ws;
    size_t off = 0;
    bf16* wcat = (bf16*)(w + off); off += (size_t)NW_TOTAL * 2;
    bf16* wqkv  = wcat;
    bf16* wproj = wqkv + NW_QKV;
    bf16* wfc1  = wproj + NW_PROJ;
    bf16* weye1 = wfc1 + NW_FC1;
    bf16* weye2 = weye1 + NW_EYE;
    bf16* wfc2  = weye2 + NW_EYE;
    bf16* hbuf  = (bf16*)(w + off); off += (size_t)TOKENS * DIM * 2;
    bf16* qkvb  = (bf16*)(w + off); off += (size_t)TOKENS * 3 * DIM * 2;
    bf16* vtb   = (bf16*)(w + off); off += (size_t)TOKENS * DIM * 2;   // V^T [b,h,d,n]
    bf16* obuf  = (bf16*)(w + off); off += (size_t)TOKENS * DIM * 2;
    bf16* abuf  = (bf16*)(w + off); off += (size_t)TOKENS * HIDDEN * 2;
    bf16* tbuf  = (bf16*)(w + off); off += (size_t)TOKENS * HIDDEN * 2;
    float* x1   = (float*)(w + off); off += (size_t)TOKENS * DIM * 4;

    convert_weights<<<4096, 256, 0, stream>>>(qkv_w, proj_w, fc1_w, eye1_w, eye2_w, fc2_w, wcat);

    ln_kernel<<<TOKENS / 4, 256, 0, stream>>>(x, n1w, n1b, hbuf);

    gemm_bt<4><<<dim3(1152 / 128, TOKENS / 128), 256, 0, stream>>>(
        hbuf, wqkv, qkv_b, qkvb, nullptr, nullptr, nullptr, vtb, 1152, 384);

    attn_kernel<<<dim3(SEQ / 128, BATCH * HEADS), 256, 0, stream>>>(qkvb, vtb, obuf);

    gemm_bt<3><<<dim3(384 / 128, TOKENS / 128), 256, 0, stream>>>(
        obuf, wproj, proj_b, nullptr, x1, x, ls1, nullptr, 384, 384);

    ln_kernel<<<TOKENS / 4, 256, 0, stream>>>(x1, n2w, n2b, hbuf);

    gemm_bt<2><<<dim3(1536 / 128, TOKENS / 128), 256, 0, stream>>>(
        hbuf, wfc1, fc1_b, abuf, nullptr, nullptr, nullptr, nullptr, 1536, 384);

    gemm_bt<0><<<dim3(1536 / 128, TOKENS / 128), 256, 0, stream>>>(
        abuf, weye1, nullptr, tbuf, nullptr, nullptr, nullptr, nullptr, 1536, 1536);

    gemm_bt<0><<<dim3(1536 / 128, TOKENS / 128), 256, 0, stream>>>(
        tbuf, weye2, nullptr, abuf, nullptr, nullptr, nullptr, nullptr, 1536, 1536);

    gemm_bt<3><<<dim3(384 / 128, TOKENS / 128), 256, 0, stream>>>(
        abuf, wfc2, fc2_b, nullptr, out, x1, ls2, nullptr, 384, 1536);
}

// Round 4
// 436.820 us; speedup vs baseline: 1.6399x; 1.2026x over previous
//
#include <hip/hip_runtime.h>
#include <math.h>

#define DIM 384
#define HEADS 6
#define HEAD_DIM 64
#define HIDDEN 1536
#define BATCH 8
#define SEQ 2048
#define TOKENS (BATCH * SEQ)

typedef __bf16 bf16;
typedef __bf16 bf16x8 __attribute__((ext_vector_type(8)));
typedef __bf16 bf16x4 __attribute__((ext_vector_type(4)));
typedef float f32x4 __attribute__((ext_vector_type(4)));
typedef int i32x4 __attribute__((ext_vector_type(4)));
typedef int i32x8 __attribute__((ext_vector_type(8)));

#define GLOAD_LDS(gp, lp)                                                      \
    __builtin_amdgcn_global_load_lds(                                          \
        (const __attribute__((address_space(1))) void*)(gp),                   \
        (__attribute__((address_space(3))) void*)(lp), 16, 0, 0)

// ---------------- weight conversion ------------------------------------------
#define NW_QKV  (1152 * 384)
#define NW_PROJ (384 * 384)
#define NW_FC1  (1536 * 384)
#define NW_EYE  (1536 * 1536)
#define NW_FC2  (384 * 1536)
#define NW_BF   (NW_QKV + NW_PROJ + NW_FC1 + NW_FC2)

__global__ void convert_weights(const float* __restrict__ qkv, const float* __restrict__ proj,
                                const float* __restrict__ fc1, const float* __restrict__ fc2,
                                bf16* __restrict__ dst) {
    int q4 = blockIdx.x * 256 + threadIdx.x;
    int stride = gridDim.x * 256;
    for (; q4 < NW_BF / 4; q4 += stride) {
        int i = q4 * 4;
        int j = i;
        const float* src;
        if (j < NW_QKV) src = qkv;
        else if ((j -= NW_QKV) < NW_PROJ) src = proj;
        else if ((j -= NW_PROJ) < NW_FC1) src = fc1;
        else { j -= NW_FC1; src = fc2; }
        float4 v = *(const float4*)(src + j);
        bf16x4 o; o[0] = (bf16)v.x; o[1] = (bf16)v.y; o[2] = (bf16)v.z; o[3] = (bf16)v.w;
        *(bf16x4*)(dst + i) = o;
    }
}

__global__ void convert_eyes_f8(const float* __restrict__ e1, const float* __restrict__ e2,
                                unsigned char* __restrict__ dst) {
    int q4 = blockIdx.x * 256 + threadIdx.x;
    int stride = gridDim.x * 256;
    for (; q4 < 2 * NW_EYE / 4; q4 += stride) {
        int i = q4 * 4;
        const float* src = (i < NW_EYE) ? e1 + i : e2 + (i - NW_EYE);
        float4 v = *(const float4*)src;
        int p = __builtin_amdgcn_cvt_pk_fp8_f32(v.x, v.y, 0, false);
        p = __builtin_amdgcn_cvt_pk_fp8_f32(v.z, v.w, p, true);
        *(int*)(dst + i) = p;
    }
}

// ---------------- LayerNorm: fp32 in -> bf16 out, one wave per token ---------
__global__ __launch_bounds__(256) void ln_kernel(const float* __restrict__ x,
                                                 const float* __restrict__ w,
                                                 const float* __restrict__ b,
                                                 bf16* __restrict__ out) {
    int wave = threadIdx.x >> 6;
    int lane = threadIdx.x & 63;
    int t = blockIdx.x * 4 + wave;
    const float* xr = x + (size_t)t * DIM;
    float v[6];
    float s = 0.f;
#pragma unroll
    for (int i = 0; i < 6; i++) { v[i] = xr[lane + 64 * i]; s += v[i]; }
#pragma unroll
    for (int m = 1; m < 64; m <<= 1) s += __shfl_xor(s, m, 64);
    float mu = s * (1.f / DIM);
    float q = 0.f;
#pragma unroll
    for (int i = 0; i < 6; i++) { float d = v[i] - mu; q += d * d; }
#pragma unroll
    for (int m = 1; m < 64; m <<= 1) q += __shfl_xor(q, m, 64);
    float rstd = rsqrtf(q * (1.f / DIM) + 1e-5f);
    bf16* orow = out + (size_t)t * DIM;
#pragma unroll
    for (int i = 0; i < 6; i++) {
        int c = lane + 64 * i;
        orow[c] = (bf16)((v[i] - mu) * rstd * w[c] + b[c]);
    }
}

// ---------------- bf16 GEMM: C[M,N] = A[M,K] @ W[N,K]^T (+ epilogue) ---------
// EPI 0: plain -> bf16   EPI 2: +bias, GELU -> fp8 out8
// EPI 3: +bias, out_f32 = resid + v*gamma
// EPI 4: qkv: +bias; Q cols scaled -> qkvb; V cols -> vtb transposed
template <int EPI>
__global__ __launch_bounds__(256) void gemm_bt(const bf16* __restrict__ A,
                                               const bf16* __restrict__ W,
                                               const float* __restrict__ bias,
                                               bf16* __restrict__ outb,
                                               float* __restrict__ outf,
                                               const float* __restrict__ resid,
                                               const float* __restrict__ gamma,
                                               bf16* __restrict__ vtb,
                                               unsigned char* __restrict__ out8,
                                               int N, int K) {
    __shared__ __attribute__((aligned(16))) bf16 As[128 * 64];
    __shared__ __attribute__((aligned(16))) bf16 Bs[128 * 64];
    int tid = threadIdx.x;
    int wave = tid >> 6, lane = tid & 63;
    int l15 = lane & 15, quad = lane >> 4;
    int bm = blockIdx.y * 128, bn = blockIdx.x * 128;
    int wm = (wave & 1) * 64, wn = (wave >> 1) * 64;
    f32x4 acc[4][4] = {};

    for (int k0 = 0; k0 < K; k0 += 64) {
#pragma unroll
        for (int i = 0; i < 4; i++) {
            int slot = i * 256 + tid;
            int rr = slot >> 3;
            int gg = (slot & 7) ^ (rr & 7);
            GLOAD_LDS(A + (size_t)(bm + rr) * K + k0 + gg * 8,
                      (char*)As + (i * 256 + wave * 64) * 16);
            GLOAD_LDS(W + (size_t)(bn + rr) * K + k0 + gg * 8,
                      (char*)Bs + (i * 256 + wave * 64) * 16);
        }
        __syncthreads();
#pragma unroll
        for (int ks = 0; ks < 2; ks++) {
            bf16x8 af[4], bfg[4];
#pragma unroll
            for (int mt = 0; mt < 4; mt++) {
                int rA = wm + mt * 16 + l15;
                af[mt] = *(const bf16x8*)((char*)As +
                         16 * (8 * rA + ((4 * ks + quad) ^ (rA & 7))));
            }
#pragma unroll
            for (int nt = 0; nt < 4; nt++) {
                int rB = wn + nt * 16 + l15;
                bfg[nt] = *(const bf16x8*)((char*)Bs +
                          16 * (8 * rB + ((4 * ks + quad) ^ (rB & 7))));
            }
#pragma unroll
            for (int mt = 0; mt < 4; mt++)
#pragma unroll
                for (int nt = 0; nt < 4; nt++)
                    acc[mt][nt] = __builtin_amdgcn_mfma_f32_16x16x32_bf16(
                        af[mt], bfg[nt], acc[mt][nt], 0, 0, 0);
        }
        __syncthreads();
    }

#pragma unroll
    for (int mt = 0; mt < 4; mt++) {
#pragma unroll
        for (int nt = 0; nt < 4; nt++) {
            int col = bn + wn + nt * 16 + l15;
            int row0 = bm + wm + mt * 16 + quad * 4;
            float v[4];
#pragma unroll
            for (int r = 0; r < 4; r++) {
                v[r] = acc[mt][nt][r];
                if (EPI >= 2) v[r] += bias[col];
                if (EPI == 2) v[r] = 0.5f * v[r] * (1.f + erff(v[r] * 0.70710678118654752f));
            }
            if (EPI == 2) {
#pragma unroll
                for (int r = 0; r < 4; r++)
                    out8[(size_t)(row0 + r) * N + col] = (unsigned char)
                        (__builtin_amdgcn_cvt_pk_fp8_f32(v[r], v[r], 0, false) & 0xff);
            } else if (EPI == 3) {
#pragma unroll
                for (int r = 0; r < 4; r++) {
                    size_t idx = (size_t)(row0 + r) * N + col;
                    outf[idx] = resid[idx] + v[r] * gamma[col];
                }
            } else if (EPI == 4) {
                if (col < 768) {  // wave-uniform per nt
                    float sc = (col < 384) ? 0.180336880f : 1.f;  // 0.125*log2(e)
#pragma unroll
                    for (int r = 0; r < 4; r++)
                        outb[(size_t)(row0 + r) * N + col] = (bf16)(v[r] * sc);
                } else {
                    int hd = col - 768;
                    int b = row0 >> 11;
                    int n0 = row0 & 2047;
                    bf16x4 pk;
#pragma unroll
                    for (int r = 0; r < 4; r++) pk[r] = (bf16)v[r];
                    *(bf16x4*)(vtb + ((size_t)(b * 384 + hd) << 11) + n0) = pk;
                }
            } else {
#pragma unroll
                for (int r = 0; r < 4; r++)
                    outb[(size_t)(row0 + r) * N + col] = (bf16)v[r];
            }
        }
    }
}

// ---------------- fp8 MX GEMM (unit scales): C = A[M,K]f8 @ W[N,K]f8^T -------
// OUT 0: -> fp8   OUT 1: -> bf16
template <int OUT>
__global__ __launch_bounds__(256) void gemm_f8(const unsigned char* __restrict__ A,
                                               const unsigned char* __restrict__ W,
                                               bf16* __restrict__ outb,
                                               unsigned char* __restrict__ out8,
                                               int N, int K) {
    __shared__ __attribute__((aligned(16))) unsigned char As[128 * 128];
    __shared__ __attribute__((aligned(16))) unsigned char Bs[128 * 128];
    int tid = threadIdx.x;
    int wave = tid >> 6, lane = tid & 63;
    int l15 = lane & 15, quad = lane >> 4;
    int bm = blockIdx.y * 128, bn = blockIdx.x * 128;
    int wm = (wave & 1) * 64, wn = (wave >> 1) * 64;
    f32x4 acc[4][4] = {};

    for (int k0 = 0; k0 < K; k0 += 128) {
#pragma unroll
        for (int i = 0; i < 4; i++) {
            int slot = i * 256 + tid;            // 1024 chunks of 16B per tile
            int rr = slot >> 3;
            int gg = (slot & 7) ^ (rr & 7);
            GLOAD_LDS(A + (size_t)(bm + rr) * K + k0 + gg * 16,
                      (char*)As + (i * 256 + wave * 64) * 16);
            GLOAD_LDS(W + (size_t)(bn + rr) * K + k0 + gg * 16,
                      (char*)Bs + (i * 256 + wave * 64) * 16);
        }
        __syncthreads();
        i32x8 af[4], bfr[4];
#pragma unroll
        for (int mt = 0; mt < 4; mt++) {
            int rA = wm + mt * 16 + l15;
            const i32x4* p = (const i32x4*)(As + 128 * rA);
            i32x4 lo = p[(2 * quad) ^ (rA & 7)];
            i32x4 hi = p[(2 * quad + 1) ^ (rA & 7)];
#pragma unroll
            for (int j = 0; j < 4; j++) { af[mt][j] = lo[j]; af[mt][4 + j] = hi[j]; }
        }
#pragma unroll
        for (int nt = 0; nt < 4; nt++) {
            int rB = wn + nt * 16 + l15;
            const i32x4* p = (const i32x4*)(Bs + 128 * rB);
            i32x4 lo = p[(2 * quad) ^ (rB & 7)];
            i32x4 hi = p[(2 * quad + 1) ^ (rB & 7)];
#pragma unroll
            for (int j = 0; j < 4; j++) { bfr[nt][j] = lo[j]; bfr[nt][4 + j] = hi[j]; }
        }
#pragma unroll
        for (int mt = 0; mt < 4; mt++)
#pragma unroll
            for (int nt = 0; nt < 4; nt++)
                acc[mt][nt] = __builtin_amdgcn_mfma_scale_f32_16x16x128_f8f6f4(
                    af[mt], bfr[nt], acc[mt][nt], 0, 0,
                    0, 0x7f7f7f7f, 0, 0x7f7f7f7f);
        __syncthreads();
    }

#pragma unroll
    for (int mt = 0; mt < 4; mt++) {
#pragma unroll
        for (int nt = 0; nt < 4; nt++) {
            int col = bn + wn + nt * 16 + l15;
            int row0 = bm + wm + mt * 16 + quad * 4;
#pragma unroll
            for (int r = 0; r < 4; r++) {
                float v = acc[mt][nt][r];
                if (OUT == 0)
                    out8[(size_t)(row0 + r) * N + col] = (unsigned char)
                        (__builtin_amdgcn_cvt_pk_fp8_f32(v, v, 0, false) & 0xff);
                else
                    outb[(size_t)(row0 + r) * N + col] = (bf16)v;
            }
        }
    }
}

// ---------------- flash attention: 128 Q rows/block, 4 waves x 32 rows -------
__global__ __launch_bounds__(256) void attn_kernel(const bf16* __restrict__ qkv,
                                                   const bf16* __restrict__ vtb,
                                                   bf16* __restrict__ o) {
    __shared__ __attribute__((aligned(16))) bf16 Ks[64 * 64];
    __shared__ __attribute__((aligned(16))) bf16 Vts[64 * 64];
    __shared__ __attribute__((aligned(16))) bf16 Ps[4][32][72];
    int tid = threadIdx.x, wave = tid >> 6, lane = tid & 63;
    int l15 = lane & 15, quad = lane >> 4;
    int bh = blockIdx.y;
    int b = bh / HEADS, h = bh - b * HEADS;
    int qr0 = blockIdx.x * 128 + wave * 32;
    const size_t rstr = 3 * DIM;
    const bf16* base = qkv + (size_t)b * SEQ * rstr;
    const bf16* vbase = vtb + ((size_t)bh << 17);

    bf16x8 aq[2][2];
#pragma unroll
    for (int qt = 0; qt < 2; qt++)
#pragma unroll
        for (int ks = 0; ks < 2; ks++)
            aq[qt][ks] = *(const bf16x8*)(base + (size_t)(qr0 + qt * 16 + l15) * rstr +
                                          h * 64 + ks * 32 + quad * 8);

    f32x4 oacc[2][4] = {};
    float lsum[2] = {0.f, 0.f};

    for (int kt = 0; kt < SEQ / 64; kt++) {
        int kb = kt * 64;
#pragma unroll
        for (int i = 0; i < 2; i++) {
            int slot = i * 256 + tid;
            int rr = slot >> 3;
            int gg = (slot & 7) ^ (rr & 7);
            GLOAD_LDS(base + (size_t)(kb + rr) * rstr + DIM + h * 64 + gg * 8,
                      (char*)Ks + (i * 256 + wave * 64) * 16);
            GLOAD_LDS(vbase + ((size_t)rr << 11) + kb + gg * 8,
                      (char*)Vts + (i * 256 + wave * 64) * 16);
        }
        __syncthreads();

        f32x4 s[2][4] = {};
#pragma unroll
        for (int ks = 0; ks < 2; ks++) {
#pragma unroll
            for (int nt = 0; nt < 4; nt++) {
                int rK = nt * 16 + l15;
                bf16x8 ak = *(const bf16x8*)((char*)Ks +
                            16 * (8 * rK + ((4 * ks + quad) ^ (rK & 7))));
#pragma unroll
                for (int qt = 0; qt < 2; qt++)
                    s[qt][nt] = __builtin_amdgcn_mfma_f32_16x16x32_bf16(
                        ak, aq[qt][ks], s[qt][nt], 0, 0, 0);
            }
        }

#pragma unroll
        for (int qt = 0; qt < 2; qt++)
#pragma unroll
            for (int nt = 0; nt < 4; nt++) {
                bf16x4 pk;
#pragma unroll
                for (int r = 0; r < 4; r++) {
                    float p = __builtin_amdgcn_exp2f(s[qt][nt][r]);
                    lsum[qt] += p;
                    pk[r] = (bf16)p;
                }
                *(bf16x4*)&Ps[wave][qt * 16 + l15][nt * 16 + quad * 4] = pk;
            }

#pragma unroll
        for (int ks = 0; ks < 2; ks++) {
            bf16x8 ap[2];
#pragma unroll
            for (int qt = 0; qt < 2; qt++)
                ap[qt] = *(const bf16x8*)&Ps[wave][qt * 16 + l15][ks * 32 + quad * 8];
#pragma unroll
            for (int dt = 0; dt < 4; dt++) {
                int rV = dt * 16 + l15;
                bf16x8 bv = *(const bf16x8*)((char*)Vts +
                            16 * (8 * rV + ((4 * ks + quad) ^ (rV & 7))));
#pragma unroll
                for (int qt = 0; qt < 2; qt++)
                    oacc[qt][dt] = __builtin_amdgcn_mfma_f32_16x16x32_bf16(
                        ap[qt], bv, oacc[qt][dt], 0, 0, 0);
            }
        }
        __syncthreads();
    }

#pragma unroll
    for (int qt = 0; qt < 2; qt++) {
        lsum[qt] += __shfl_xor(lsum[qt], 16, 64);
        lsum[qt] += __shfl_xor(lsum[qt], 32, 64);
    }
#pragma unroll
    for (int qt = 0; qt < 2; qt++)
#pragma unroll
        for (int r = 0; r < 4; r++) {
            float lt = __shfl(lsum[qt], 4 * quad + r, 64);
            float inv = 1.f / lt;
            int qrow = qr0 + qt * 16 + quad * 4 + r;
            bf16* orow = o + ((size_t)(b * SEQ + qrow)) * DIM + h * 64;
#pragma unroll
            for (int dt = 0; dt < 4; dt++) orow[dt * 16 + l15] = (bf16)(oacc[qt][dt][r] * inv);
        }
}

// ---------------- orchestration ----------------------------------------------
extern "C" void kernel_launch(void* const* d_in, const int* in_sizes, int n_in,
                              void* d_out, int out_size, void* d_ws, size_t ws_size,
                              hipStream_t stream) {
    const float* x      = (const float*)d_in[0];
    const float* qkv_w  = (const float*)d_in[1];
    const float* qkv_b  = (const float*)d_in[2];
    const float* proj_w = (const float*)d_in[3];
    const float* proj_b = (const float*)d_in[4];
    const float* fc1_w  = (const float*)d_in[5];
    const float* fc1_b  = (const float*)d_in[6];
    const float* eye1_w = (const float*)d_in[7];
    const float* eye2_w = (const float*)d_in[8];
    const float* fc2_w  = (const float*)d_in[9];
    const float* fc2_b  = (const float*)d_in[10];
    const float* n1w    = (const float*)d_in[11];
    const float* n1b    = (const float*)d_in[12];
    const float* n2w    = (const float*)d_in[13];
    const float* n2b    = (const float*)d_in[14];
    const float* ls1    = (const float*)d_in[15];
    const float* ls2    = (const float*)d_in[16];
    float* out = (float*)d_out;

    char* w = (char*)d_ws;
    size_t off = 0;
    bf16* wbf = (bf16*)(w + off); off += (size_t)NW_BF * 2;
    bf16* wqkv  = wbf;
    bf16* wproj = wqkv + NW_QKV;
    bf16* wfc1  = wproj + NW_PROJ;
    bf16* wfc2  = wfc1 + NW_FC1;
    unsigned char* weye8 = (unsigned char*)(w + off); off += 2 * (size_t)NW_EYE;
    bf16* hbuf  = (bf16*)(w + off); off += (size_t)TOKENS * DIM * 2;
    bf16* qkvb  = (bf16*)(w + off); off += (size_t)TOKENS * 3 * DIM * 2;
    bf16* vtb   = (bf16*)(w + off); off += (size_t)TOKENS * DIM * 2;
    bf16* obuf  = (bf16*)(w + off); off += (size_t)TOKENS * DIM * 2;
    bf16* abuf  = (bf16*)(w + off); off += (size_t)TOKENS * HIDDEN * 2;
    float* x1   = (float*)(w + off); off += (size_t)TOKENS * DIM * 4;
    // fp8 overlays on dead regions (stream-ordered reuse):
    unsigned char* abuf8 = (unsigned char*)qkvb;  // fc1 out; qkvb dead after attn
    unsigned char* tbuf8 = (unsigned char*)vtb;   // eye1 out; vtb+obuf dead after proj

    convert_weights<<<1728, 256, 0, stream>>>(qkv_w, proj_w, fc1_w, fc2_w, wbf);
    convert_eyes_f8<<<4096, 256, 0, stream>>>(eye1_w, eye2_w, weye8);

    ln_kernel<<<TOKENS / 4, 256, 0, stream>>>(x, n1w, n1b, hbuf);

    gemm_bt<4><<<dim3(1152 / 128, TOKENS / 128), 256, 0, stream>>>(
        hbuf, wqkv, qkv_b, qkvb, nullptr, nullptr, nullptr, vtb, nullptr, 1152, 384);

    attn_kernel<<<dim3(SEQ / 128, BATCH * HEADS), 256, 0, stream>>>(qkvb, vtb, obuf);

    gemm_bt<3><<<dim3(384 / 128, TOKENS / 128), 256, 0, stream>>>(
        obuf, wproj, proj_b, nullptr, x1, x, ls1, nullptr, nullptr, 384, 384);

    ln_kernel<<<TOKENS / 4, 256, 0, stream>>>(x1, n2w, n2b, hbuf);

    gemm_bt<2><<<dim3(1536 / 128, TOKENS / 128), 256, 0, stream>>>(
        hbuf, wfc1, fc1_b, nullptr, nullptr, nullptr, nullptr, nullptr, abuf8, 1536, 384);

    gemm_f8<0><<<dim3(1536 / 128, TOKENS / 128), 256, 0, stream>>>(
        abuf8, weye8, nullptr, tbuf8, 1536, 1536);

    gemm_f8<1><<<dim3(1536 / 128, TOKENS / 128), 256, 0, stream>>>(
        tbuf8, weye8 + NW_EYE, abuf, nullptr, 1536, 1536);

    gemm_bt<3><<<dim3(384 / 128, TOKENS / 128), 256, 0, stream>>>(
        abuf, wfc2, fc2_b, nullptr, out, x1, ls2, nullptr, nullptr, 384, 1536);
}

// Round 5
// 420.616 us; speedup vs baseline: 1.7030x; 1.0385x over previous
//
#include <hip/hip_runtime.h>
#include <math.h>

#define DIM 384
#define HEADS 6
#define HEAD_DIM 64
#define HIDDEN 1536
#define BATCH 8
#define SEQ 2048
#define TOKENS (BATCH * SEQ)

typedef __bf16 bf16;
typedef __bf16 bf16x8 __attribute__((ext_vector_type(8)));
typedef __bf16 bf16x4 __attribute__((ext_vector_type(4)));
typedef float f32x4 __attribute__((ext_vector_type(4)));
typedef int i32x4 __attribute__((ext_vector_type(4)));
typedef int i32x8 __attribute__((ext_vector_type(8)));

#define GLOAD_LDS(gp, lp)                                                      \
    __builtin_amdgcn_global_load_lds(                                          \
        (const __attribute__((address_space(1))) void*)(gp),                   \
        (__attribute__((address_space(3))) void*)(lp), 16, 0, 0)

// ---------------- weight conversion ------------------------------------------
#define NW_QKV  (1152 * 384)
#define NW_PROJ (384 * 384)
#define NW_FC1  (1536 * 384)
#define NW_EYE  (1536 * 1536)
#define NW_FC2  (384 * 1536)
#define NW_BF   (NW_QKV + NW_PROJ + NW_FC1 + NW_FC2)

__global__ void convert_weights(const float* __restrict__ qkv, const float* __restrict__ proj,
                                const float* __restrict__ fc1, const float* __restrict__ fc2,
                                bf16* __restrict__ dst) {
    int q4 = blockIdx.x * 256 + threadIdx.x;
    int stride = gridDim.x * 256;
    for (; q4 < NW_BF / 4; q4 += stride) {
        int i = q4 * 4;
        int j = i;
        const float* src;
        if (j < NW_QKV) src = qkv;
        else if ((j -= NW_QKV) < NW_PROJ) src = proj;
        else if ((j -= NW_PROJ) < NW_FC1) src = fc1;
        else { j -= NW_FC1; src = fc2; }
        float4 v = *(const float4*)(src + j);
        bf16x4 o; o[0] = (bf16)v.x; o[1] = (bf16)v.y; o[2] = (bf16)v.z; o[3] = (bf16)v.w;
        *(bf16x4*)(dst + i) = o;
    }
}

__global__ void convert_eyes_f8(const float* __restrict__ e1, const float* __restrict__ e2,
                                unsigned char* __restrict__ dst) {
    int q4 = blockIdx.x * 256 + threadIdx.x;
    int stride = gridDim.x * 256;
    for (; q4 < 2 * NW_EYE / 4; q4 += stride) {
        int i = q4 * 4;
        const float* src = (i < NW_EYE) ? e1 + i : e2 + (i - NW_EYE);
        float4 v = *(const float4*)src;
        int p = __builtin_amdgcn_cvt_pk_fp8_f32(v.x, v.y, 0, false);
        p = __builtin_amdgcn_cvt_pk_fp8_f32(v.z, v.w, p, true);
        *(int*)(dst + i) = p;
    }
}

// ---------------- LayerNorm: fp32 in -> bf16 out, one wave per token ---------
__global__ __launch_bounds__(256) void ln_kernel(const float* __restrict__ x,
                                                 const float* __restrict__ w,
                                                 const float* __restrict__ b,
                                                 bf16* __restrict__ out) {
    int wave = threadIdx.x >> 6;
    int lane = threadIdx.x & 63;
    int t = blockIdx.x * 4 + wave;
    const float* xr = x + (size_t)t * DIM;
    float v[6];
    float s = 0.f;
#pragma unroll
    for (int i = 0; i < 6; i++) { v[i] = xr[lane + 64 * i]; s += v[i]; }
#pragma unroll
    for (int m = 1; m < 64; m <<= 1) s += __shfl_xor(s, m, 64);
    float mu = s * (1.f / DIM);
    float q = 0.f;
#pragma unroll
    for (int i = 0; i < 6; i++) { float d = v[i] - mu; q += d * d; }
#pragma unroll
    for (int m = 1; m < 64; m <<= 1) q += __shfl_xor(q, m, 64);
    float rstd = rsqrtf(q * (1.f / DIM) + 1e-5f);
    bf16* orow = out + (size_t)t * DIM;
#pragma unroll
    for (int i = 0; i < 6; i++) {
        int c = lane + 64 * i;
        orow[c] = (bf16)((v[i] - mu) * rstd * w[c] + b[c]);
    }
}

// ---------------- bf16 GEMM: C[M,N] = A[M,K] @ W[N,K]^T (+ epilogue) ---------
// EPI 0: plain -> bf16   EPI 2: +bias, GELU -> fp8 out8
// EPI 3: +bias, out_f32 = resid + v*gamma
// EPI 4: qkv: +bias; Q cols scaled -> qkvb; V cols -> vtb transposed
template <int EPI>
__global__ __launch_bounds__(256) void gemm_bt(const bf16* __restrict__ A,
                                               const bf16* __restrict__ W,
                                               const float* __restrict__ bias,
                                               bf16* __restrict__ outb,
                                               float* __restrict__ outf,
                                               const float* __restrict__ resid,
                                               const float* __restrict__ gamma,
                                               bf16* __restrict__ vtb,
                                               unsigned char* __restrict__ out8,
                                               int N, int K) {
    __shared__ __attribute__((aligned(16))) bf16 As[128 * 64];
    __shared__ __attribute__((aligned(16))) bf16 Bs[128 * 64];
    int tid = threadIdx.x;
    int wave = tid >> 6, lane = tid & 63;
    int l15 = lane & 15, quad = lane >> 4;
    int bm = blockIdx.y * 128, bn = blockIdx.x * 128;
    int wm = (wave & 1) * 64, wn = (wave >> 1) * 64;
    f32x4 acc[4][4] = {};

    for (int k0 = 0; k0 < K; k0 += 64) {
#pragma unroll
        for (int i = 0; i < 4; i++) {
            int slot = i * 256 + tid;
            int rr = slot >> 3;
            int gg = (slot & 7) ^ (rr & 7);
            GLOAD_LDS(A + (size_t)(bm + rr) * K + k0 + gg * 8,
                      (char*)As + (i * 256 + wave * 64) * 16);
            GLOAD_LDS(W + (size_t)(bn + rr) * K + k0 + gg * 8,
                      (char*)Bs + (i * 256 + wave * 64) * 16);
        }
        __syncthreads();
#pragma unroll
        for (int ks = 0; ks < 2; ks++) {
            bf16x8 af[4], bfg[4];
#pragma unroll
            for (int mt = 0; mt < 4; mt++) {
                int rA = wm + mt * 16 + l15;
                af[mt] = *(const bf16x8*)((char*)As +
                         16 * (8 * rA + ((4 * ks + quad) ^ (rA & 7))));
            }
#pragma unroll
            for (int nt = 0; nt < 4; nt++) {
                int rB = wn + nt * 16 + l15;
                bfg[nt] = *(const bf16x8*)((char*)Bs +
                          16 * (8 * rB + ((4 * ks + quad) ^ (rB & 7))));
            }
#pragma unroll
            for (int mt = 0; mt < 4; mt++)
#pragma unroll
                for (int nt = 0; nt < 4; nt++)
                    acc[mt][nt] = __builtin_amdgcn_mfma_f32_16x16x32_bf16(
                        af[mt], bfg[nt], acc[mt][nt], 0, 0, 0);
        }
        __syncthreads();
    }

#pragma unroll
    for (int mt = 0; mt < 4; mt++) {
#pragma unroll
        for (int nt = 0; nt < 4; nt++) {
            int col = bn + wn + nt * 16 + l15;
            int row0 = bm + wm + mt * 16 + quad * 4;
            float v[4];
#pragma unroll
            for (int r = 0; r < 4; r++) {
                v[r] = acc[mt][nt][r];
                if (EPI >= 2) v[r] += bias[col];
                if (EPI == 2) v[r] = 0.5f * v[r] * (1.f + erff(v[r] * 0.70710678118654752f));
            }
            if (EPI == 2) {
#pragma unroll
                for (int r = 0; r < 4; r++)
                    out8[(size_t)(row0 + r) * N + col] = (unsigned char)
                        (__builtin_amdgcn_cvt_pk_fp8_f32(v[r], v[r], 0, false) & 0xff);
            } else if (EPI == 3) {
#pragma unroll
                for (int r = 0; r < 4; r++) {
                    size_t idx = (size_t)(row0 + r) * N + col;
                    outf[idx] = resid[idx] + v[r] * gamma[col];
                }
            } else if (EPI == 4) {
                if (col < 768) {  // wave-uniform per nt
                    float sc = (col < 384) ? 0.180336880f : 1.f;  // 0.125*log2(e)
#pragma unroll
                    for (int r = 0; r < 4; r++)
                        outb[(size_t)(row0 + r) * N + col] = (bf16)(v[r] * sc);
                } else {
                    int hd = col - 768;
                    int b = row0 >> 11;
                    int n0 = row0 & 2047;
                    bf16x4 pk;
#pragma unroll
                    for (int r = 0; r < 4; r++) pk[r] = (bf16)v[r];
                    *(bf16x4*)(vtb + ((size_t)(b * 384 + hd) << 11) + n0) = pk;
                }
            } else {
#pragma unroll
                for (int r = 0; r < 4; r++)
                    outb[(size_t)(row0 + r) * N + col] = (bf16)v[r];
            }
        }
    }
}

// ---------------- fp8 MX GEMM (unit scales): C = A[M,K]f8 @ W[N,K]f8^T -------
// OUT 0: -> fp8   OUT 1: -> bf16
template <int OUT>
__global__ __launch_bounds__(256) void gemm_f8(const unsigned char* __restrict__ A,
                                               const unsigned char* __restrict__ W,
                                               bf16* __restrict__ outb,
                                               unsigned char* __restrict__ out8,
                                               int N, int K) {
    __shared__ __attribute__((aligned(16))) unsigned char As[128 * 128];
    __shared__ __attribute__((aligned(16))) unsigned char Bs[128 * 128];
    int tid = threadIdx.x;
    int wave = tid >> 6, lane = tid & 63;
    int l15 = lane & 15, quad = lane >> 4;
    int bm = blockIdx.y * 128, bn = blockIdx.x * 128;
    int wm = (wave & 1) * 64, wn = (wave >> 1) * 64;
    f32x4 acc[4][4] = {};

    for (int k0 = 0; k0 < K; k0 += 128) {
#pragma unroll
        for (int i = 0; i < 4; i++) {
            int slot = i * 256 + tid;            // 1024 chunks of 16B per tile
            int rr = slot >> 3;
            int gg = (slot & 7) ^ (rr & 7);
            GLOAD_LDS(A + (size_t)(bm + rr) * K + k0 + gg * 16,
                      (char*)As + (i * 256 + wave * 64) * 16);
            GLOAD_LDS(W + (size_t)(bn + rr) * K + k0 + gg * 16,
                      (char*)Bs + (i * 256 + wave * 64) * 16);
        }
        __syncthreads();
        i32x8 af[4], bfr[4];
#pragma unroll
        for (int mt = 0; mt < 4; mt++) {
            int rA = wm + mt * 16 + l15;
            const i32x4* p = (const i32x4*)(As + 128 * rA);
            i32x4 lo = p[(2 * quad) ^ (rA & 7)];
            i32x4 hi = p[(2 * quad + 1) ^ (rA & 7)];
#pragma unroll
            for (int j = 0; j < 4; j++) { af[mt][j] = lo[j]; af[mt][4 + j] = hi[j]; }
        }
#pragma unroll
        for (int nt = 0; nt < 4; nt++) {
            int rB = wn + nt * 16 + l15;
            const i32x4* p = (const i32x4*)(Bs + 128 * rB);
            i32x4 lo = p[(2 * quad) ^ (rB & 7)];
            i32x4 hi = p[(2 * quad + 1) ^ (rB & 7)];
#pragma unroll
            for (int j = 0; j < 4; j++) { bfr[nt][j] = lo[j]; bfr[nt][4 + j] = hi[j]; }
        }
#pragma unroll
        for (int mt = 0; mt < 4; mt++)
#pragma unroll
            for (int nt = 0; nt < 4; nt++)
                acc[mt][nt] = __builtin_amdgcn_mfma_scale_f32_16x16x128_f8f6f4(
                    af[mt], bfr[nt], acc[mt][nt], 0, 0,
                    0, 0x7f7f7f7f, 0, 0x7f7f7f7f);
        __syncthreads();
    }

#pragma unroll
    for (int mt = 0; mt < 4; mt++) {
#pragma unroll
        for (int nt = 0; nt < 4; nt++) {
            int col = bn + wn + nt * 16 + l15;
            int row0 = bm + wm + mt * 16 + quad * 4;
#pragma unroll
            for (int r = 0; r < 4; r++) {
                float v = acc[mt][nt][r];
                if (OUT == 0)
                    out8[(size_t)(row0 + r) * N + col] = (unsigned char)
                        (__builtin_amdgcn_cvt_pk_fp8_f32(v, v, 0, false) & 0xff);
                else
                    outb[(size_t)(row0 + r) * N + col] = (bf16)v;
            }
        }
    }
}

// ---------------- flash attention: 128 Q rows/block, double-buffered K/V -----
__global__ __launch_bounds__(256) void attn_kernel(const bf16* __restrict__ qkv,
                                                   const bf16* __restrict__ vtb,
                                                   bf16* __restrict__ o) {
    __shared__ __attribute__((aligned(16))) bf16 Ks[2][64 * 64];
    __shared__ __attribute__((aligned(16))) bf16 Vts[2][64 * 64];
    __shared__ __attribute__((aligned(16))) bf16 Ps[4][32][72];
    int tid = threadIdx.x, wave = tid >> 6, lane = tid & 63;
    int l15 = lane & 15, quad = lane >> 4;
    int bh = blockIdx.y;
    int b = bh / HEADS, h = bh - b * HEADS;
    int qr0 = blockIdx.x * 128 + wave * 32;
    const size_t rstr = 3 * DIM;
    const bf16* base = qkv + (size_t)b * SEQ * rstr;
    const bf16* vbase = vtb + ((size_t)bh << 17);

    // staging address components (loop-invariant)
    int slot0 = tid, slot1 = 256 + tid;
    int rr0 = slot0 >> 3, gg0 = (slot0 & 7) ^ (rr0 & 7);
    int rr1 = slot1 >> 3, gg1 = (slot1 & 7) ^ (rr1 & 7);
    const bf16* kg0 = base + (size_t)rr0 * rstr + DIM + h * 64 + gg0 * 8;
    const bf16* kg1 = base + (size_t)rr1 * rstr + DIM + h * 64 + gg1 * 8;
    const bf16* vg0 = vbase + ((size_t)rr0 << 11) + gg0 * 8;
    const bf16* vg1 = vbase + ((size_t)rr1 << 11) + gg1 * 8;
    int ldsoff0 = (wave * 64) * 16;          // bytes into a 8 KB buffer
    int ldsoff1 = (256 + wave * 64) * 16;

    bf16x8 aq[2][2];
#pragma unroll
    for (int qt = 0; qt < 2; qt++)
#pragma unroll
        for (int ks = 0; ks < 2; ks++)
            aq[qt][ks] = *(const bf16x8*)(base + (size_t)(qr0 + qt * 16 + l15) * rstr +
                                          h * 64 + ks * 32 + quad * 8);

    f32x4 oacc[2][4] = {};
    float lsum[2] = {0.f, 0.f};

    // prologue: stage tile 0 into buffer 0
    {
        GLOAD_LDS(kg0, (char*)Ks[0] + ldsoff0);
        GLOAD_LDS(kg1, (char*)Ks[0] + ldsoff1);
        GLOAD_LDS(vg0, (char*)Vts[0] + ldsoff0);
        GLOAD_LDS(vg1, (char*)Vts[0] + ldsoff1);
    }

    for (int kt = 0; kt < SEQ / 64; kt++) {
        int cur = kt & 1;
        __syncthreads();  // drains stage(kt) and prior compute's LDS reads
        if (kt < SEQ / 64 - 1) {
            size_t kb = (size_t)(kt + 1) * 64;
            GLOAD_LDS(kg0 + kb * rstr, (char*)Ks[cur ^ 1] + ldsoff0);
            GLOAD_LDS(kg1 + kb * rstr, (char*)Ks[cur ^ 1] + ldsoff1);
            GLOAD_LDS(vg0 + kb, (char*)Vts[cur ^ 1] + ldsoff0);
            GLOAD_LDS(vg1 + kb, (char*)Vts[cur ^ 1] + ldsoff1);
        }

        f32x4 s[2][4] = {};
#pragma unroll
        for (int ks = 0; ks < 2; ks++) {
#pragma unroll
            for (int nt = 0; nt < 4; nt++) {
                int rK = nt * 16 + l15;
                bf16x8 ak = *(const bf16x8*)((char*)Ks[cur] +
                            16 * (8 * rK + ((4 * ks + quad) ^ (rK & 7))));
#pragma unroll
                for (int qt = 0; qt < 2; qt++)
                    s[qt][nt] = __builtin_amdgcn_mfma_f32_16x16x32_bf16(
                        ak, aq[qt][ks], s[qt][nt], 0, 0, 0);
            }
        }

#pragma unroll
        for (int qt = 0; qt < 2; qt++)
#pragma unroll
            for (int nt = 0; nt < 4; nt++) {
                bf16x4 pk;
#pragma unroll
                for (int r = 0; r < 4; r++) {
                    float p = __builtin_amdgcn_exp2f(s[qt][nt][r]);
                    lsum[qt] += p;
                    pk[r] = (bf16)p;
                }
                *(bf16x4*)&Ps[wave][qt * 16 + l15][nt * 16 + quad * 4] = pk;
            }

#pragma unroll
        for (int ks = 0; ks < 2; ks++) {
            bf16x8 ap[2];
#pragma unroll
            for (int qt = 0; qt < 2; qt++)
                ap[qt] = *(const bf16x8*)&Ps[wave][qt * 16 + l15][ks * 32 + quad * 8];
#pragma unroll
            for (int dt = 0; dt < 4; dt++) {
                int rV = dt * 16 + l15;
                bf16x8 bv = *(const bf16x8*)((char*)Vts[cur] +
                            16 * (8 * rV + ((4 * ks + quad) ^ (rV & 7))));
#pragma unroll
                for (int qt = 0; qt < 2; qt++)
                    oacc[qt][dt] = __builtin_amdgcn_mfma_f32_16x16x32_bf16(
                        ap[qt], bv, oacc[qt][dt], 0, 0, 0);
            }
        }
    }

#pragma unroll
    for (int qt = 0; qt < 2; qt++) {
        lsum[qt] += __shfl_xor(lsum[qt], 16, 64);
        lsum[qt] += __shfl_xor(lsum[qt], 32, 64);
    }
#pragma unroll
    for (int qt = 0; qt < 2; qt++)
#pragma unroll
        for (int r = 0; r < 4; r++) {
            float lt = __shfl(lsum[qt], 4 * quad + r, 64);
            float inv = 1.f / lt;
            int qrow = qr0 + qt * 16 + quad * 4 + r;
            bf16* orow = o + ((size_t)(b * SEQ + qrow)) * DIM + h * 64;
#pragma unroll
            for (int dt = 0; dt < 4; dt++) orow[dt * 16 + l15] = (bf16)(oacc[qt][dt][r] * inv);
        }
}

// ---------------- orchestration ----------------------------------------------
extern "C" void kernel_launch(void* const* d_in, const int* in_sizes, int n_in,
                              void* d_out, int out_size, void* d_ws, size_t ws_size,
                              hipStream_t stream) {
    const float* x      = (const float*)d_in[0];
    const float* qkv_w  = (const float*)d_in[1];
    const float* qkv_b  = (const float*)d_in[2];
    const float* proj_w = (const float*)d_in[3];
    const float* proj_b = (const float*)d_in[4];
    const float* fc1_w  = (const float*)d_in[5];
    const float* fc1_b  = (const float*)d_in[6];
    const float* eye1_w = (const float*)d_in[7];
    const float* eye2_w = (const float*)d_in[8];
    const float* fc2_w  = (const float*)d_in[9];
    const float* fc2_b  = (const float*)d_in[10];
    const float* n1w    = (const float*)d_in[11];
    const float* n1b    = (const float*)d_in[12];
    const float* n2w    = (const float*)d_in[13];
    const float* n2b    = (const float*)d_in[14];
    const float* ls1    = (const float*)d_in[15];
    const float* ls2    = (const float*)d_in[16];
    float* out = (float*)d_out;

    char* w = (char*)d_ws;
    size_t off = 0;
    bf16* wbf = (bf16*)(w + off); off += (size_t)NW_BF * 2;
    bf16* wqkv  = wbf;
    bf16* wproj = wqkv + NW_QKV;
    bf16* wfc1  = wproj + NW_PROJ;
    bf16* wfc2  = wfc1 + NW_FC1;
    unsigned char* weye8 = (unsigned char*)(w + off); off += 2 * (size_t)NW_EYE;
    bf16* hbuf  = (bf16*)(w + off); off += (size_t)TOKENS * DIM * 2;
    bf16* qkvb  = (bf16*)(w + off); off += (size_t)TOKENS * 3 * DIM * 2;
    bf16* vtb   = (bf16*)(w + off); off += (size_t)TOKENS * DIM * 2;
    bf16* obuf  = (bf16*)(w + off); off += (size_t)TOKENS * DIM * 2;
    bf16* abuf  = (bf16*)(w + off); off += (size_t)TOKENS * HIDDEN * 2;
    float* x1   = (float*)(w + off); off += (size_t)TOKENS * DIM * 4;
    // fp8 overlays on dead regions (stream-ordered reuse):
    unsigned char* abuf8 = (unsigned char*)qkvb;  // fc1 out; qkvb dead after attn
    unsigned char* tbuf8 = (unsigned char*)vtb;   // eye1 out; vtb+obuf dead after proj

    convert_weights<<<1728, 256, 0, stream>>>(qkv_w, proj_w, fc1_w, fc2_w, wbf);
    convert_eyes_f8<<<4096, 256, 0, stream>>>(eye1_w, eye2_w, weye8);

    ln_kernel<<<TOKENS / 4, 256, 0, stream>>>(x, n1w, n1b, hbuf);

    gemm_bt<4><<<dim3(1152 / 128, TOKENS / 128), 256, 0, stream>>>(
        hbuf, wqkv, qkv_b, qkvb, nullptr, nullptr, nullptr, vtb, nullptr, 1152, 384);

    attn_kernel<<<dim3(SEQ / 128, BATCH * HEADS), 256, 0, stream>>>(qkvb, vtb, obuf);

    gemm_bt<3><<<dim3(384 / 128, TOKENS / 128), 256, 0, stream>>>(
        obuf, wproj, proj_b, nullptr, x1, x, ls1, nullptr, nullptr, 384, 384);

    ln_kernel<<<TOKENS / 4, 256, 0, stream>>>(x1, n2w, n2b, hbuf);

    gemm_bt<2><<<dim3(1536 / 128, TOKENS / 128), 256, 0, stream>>>(
        hbuf, wfc1, fc1_b, nullptr, nullptr, nullptr, nullptr, nullptr, abuf8, 1536, 384);

    gemm_f8<0><<<dim3(1536 / 128, TOKENS / 128), 256, 0, stream>>>(
        abuf8, weye8, nullptr, tbuf8, 1536, 1536);

    gemm_f8<1><<<dim3(1536 / 128, TOKENS / 128), 256, 0, stream>>>(
        tbuf8, weye8 + NW_EYE, abuf, nullptr, 1536, 1536);

    gemm_bt<3><<<dim3(384 / 128, TOKENS / 128), 256, 0, stream>>>(
        abuf, wfc2, fc2_b, nullptr, out, x1, ls2, nullptr, nullptr, 384, 1536);
}

// Round 6
// 409.164 us; speedup vs baseline: 1.7507x; 1.0280x over previous
//
#include <hip/hip_runtime.h>
#include <math.h>

#define DIM 384
#define HEADS 6
#define HEAD_DIM 64
#define HIDDEN 1536
#define BATCH 8
#define SEQ 2048
#define TOKENS (BATCH * SEQ)

typedef __bf16 bf16;
typedef __bf16 bf16x8 __attribute__((ext_vector_type(8)));
typedef __bf16 bf16x4 __attribute__((ext_vector_type(4)));
typedef float f32x4 __attribute__((ext_vector_type(4)));
typedef int i32x4 __attribute__((ext_vector_type(4)));
typedef int i32x8 __attribute__((ext_vector_type(8)));

#define GLOAD_LDS(gp, lp)                                                      \
    __builtin_amdgcn_global_load_lds(                                          \
        (const __attribute__((address_space(1))) void*)(gp),                   \
        (__attribute__((address_space(3))) void*)(lp), 16, 0, 0)

// ---------------- weight conversion ------------------------------------------
#define NW_QKV  (1152 * 384)
#define NW_PROJ (384 * 384)
#define NW_FC1  (1536 * 384)
#define NW_EYE  (1536 * 1536)
#define NW_FC2  (384 * 1536)
#define NW_BF   (NW_QKV + NW_PROJ + NW_FC1 + NW_FC2)

__global__ void convert_weights(const float* __restrict__ qkv, const float* __restrict__ proj,
                                const float* __restrict__ fc1, const float* __restrict__ fc2,
                                bf16* __restrict__ dst) {
    int q4 = blockIdx.x * 256 + threadIdx.x;
    int stride = gridDim.x * 256;
    for (; q4 < NW_BF / 4; q4 += stride) {
        int i = q4 * 4;
        int j = i;
        const float* src;
        if (j < NW_QKV) src = qkv;
        else if ((j -= NW_QKV) < NW_PROJ) src = proj;
        else if ((j -= NW_PROJ) < NW_FC1) src = fc1;
        else { j -= NW_FC1; src = fc2; }
        float4 v = *(const float4*)(src + j);
        bf16x4 o; o[0] = (bf16)v.x; o[1] = (bf16)v.y; o[2] = (bf16)v.z; o[3] = (bf16)v.w;
        *(bf16x4*)(dst + i) = o;
    }
}

__global__ void convert_eyes_f8(const float* __restrict__ e1, const float* __restrict__ e2,
                                unsigned char* __restrict__ dst) {
    int q4 = blockIdx.x * 256 + threadIdx.x;
    int stride = gridDim.x * 256;
    for (; q4 < 2 * NW_EYE / 4; q4 += stride) {
        int i = q4 * 4;
        const float* src = (i < NW_EYE) ? e1 + i : e2 + (i - NW_EYE);
        float4 v = *(const float4*)src;
        int p = __builtin_amdgcn_cvt_pk_fp8_f32(v.x, v.y, 0, false);
        p = __builtin_amdgcn_cvt_pk_fp8_f32(v.z, v.w, p, true);
        *(int*)(dst + i) = p;
    }
}

// ---------------- LayerNorm: fp32 in -> bf16 out, one wave per token ---------
__global__ __launch_bounds__(256) void ln_kernel(const float* __restrict__ x,
                                                 const float* __restrict__ w,
                                                 const float* __restrict__ b,
                                                 bf16* __restrict__ out) {
    int wave = threadIdx.x >> 6;
    int lane = threadIdx.x & 63;
    int t = blockIdx.x * 4 + wave;
    const float* xr = x + (size_t)t * DIM;
    float v[6];
    float s = 0.f;
#pragma unroll
    for (int i = 0; i < 6; i++) { v[i] = xr[lane + 64 * i]; s += v[i]; }
#pragma unroll
    for (int m = 1; m < 64; m <<= 1) s += __shfl_xor(s, m, 64);
    float mu = s * (1.f / DIM);
    float q = 0.f;
#pragma unroll
    for (int i = 0; i < 6; i++) { float d = v[i] - mu; q += d * d; }
#pragma unroll
    for (int m = 1; m < 64; m <<= 1) q += __shfl_xor(q, m, 64);
    float rstd = rsqrtf(q * (1.f / DIM) + 1e-5f);
    bf16* orow = out + (size_t)t * DIM;
#pragma unroll
    for (int i = 0; i < 6; i++) {
        int c = lane + 64 * i;
        orow[c] = (bf16)((v[i] - mu) * rstd * w[c] + b[c]);
    }
}

// ---------------- bf16 GEMM: C[M,N] = A[M,K] @ W[N,K]^T (+ epilogue) ---------
// EPI 0: plain -> bf16   EPI 2: +bias, GELU -> fp8 out8
// EPI 3: +bias, out_f32 = resid + v*gamma
// EPI 4: qkv: +bias; Q cols scaled -> qkvb; V cols -> vtb transposed
template <int EPI>
__global__ __launch_bounds__(256) void gemm_bt(const bf16* __restrict__ A,
                                               const bf16* __restrict__ W,
                                               const float* __restrict__ bias,
                                               bf16* __restrict__ outb,
                                               float* __restrict__ outf,
                                               const float* __restrict__ resid,
                                               const float* __restrict__ gamma,
                                               bf16* __restrict__ vtb,
                                               unsigned char* __restrict__ out8,
                                               int N, int K) {
    __shared__ __attribute__((aligned(16))) bf16 As[128 * 64];
    __shared__ __attribute__((aligned(16))) bf16 Bs[128 * 64];
    int tid = threadIdx.x;
    int wave = tid >> 6, lane = tid & 63;
    int l15 = lane & 15, quad = lane >> 4;
    int bm = blockIdx.y * 128, bn = blockIdx.x * 128;
    int wm = (wave & 1) * 64, wn = (wave >> 1) * 64;
    f32x4 acc[4][4] = {};

    for (int k0 = 0; k0 < K; k0 += 64) {
#pragma unroll
        for (int i = 0; i < 4; i++) {
            int slot = i * 256 + tid;
            int rr = slot >> 3;
            int gg = (slot & 7) ^ (rr & 7);
            GLOAD_LDS(A + (size_t)(bm + rr) * K + k0 + gg * 8,
                      (char*)As + (i * 256 + wave * 64) * 16);
            GLOAD_LDS(W + (size_t)(bn + rr) * K + k0 + gg * 8,
                      (char*)Bs + (i * 256 + wave * 64) * 16);
        }
        __syncthreads();
#pragma unroll
        for (int ks = 0; ks < 2; ks++) {
            bf16x8 af[4], bfg[4];
#pragma unroll
            for (int mt = 0; mt < 4; mt++) {
                int rA = wm + mt * 16 + l15;
                af[mt] = *(const bf16x8*)((char*)As +
                         16 * (8 * rA + ((4 * ks + quad) ^ (rA & 7))));
            }
#pragma unroll
            for (int nt = 0; nt < 4; nt++) {
                int rB = wn + nt * 16 + l15;
                bfg[nt] = *(const bf16x8*)((char*)Bs +
                          16 * (8 * rB + ((4 * ks + quad) ^ (rB & 7))));
            }
#pragma unroll
            for (int mt = 0; mt < 4; mt++)
#pragma unroll
                for (int nt = 0; nt < 4; nt++)
                    acc[mt][nt] = __builtin_amdgcn_mfma_f32_16x16x32_bf16(
                        af[mt], bfg[nt], acc[mt][nt], 0, 0, 0);
        }
        __syncthreads();
    }

#pragma unroll
    for (int mt = 0; mt < 4; mt++) {
#pragma unroll
        for (int nt = 0; nt < 4; nt++) {
            int col = bn + wn + nt * 16 + l15;
            int row0 = bm + wm + mt * 16 + quad * 4;
            float v[4];
#pragma unroll
            for (int r = 0; r < 4; r++) {
                v[r] = acc[mt][nt][r];
                if (EPI >= 2) v[r] += bias[col];
                if (EPI == 2) v[r] = 0.5f * v[r] * (1.f + erff(v[r] * 0.70710678118654752f));
            }
            if (EPI == 2) {
#pragma unroll
                for (int r = 0; r < 4; r++)
                    out8[(size_t)(row0 + r) * N + col] = (unsigned char)
                        (__builtin_amdgcn_cvt_pk_fp8_f32(v[r], v[r], 0, false) & 0xff);
            } else if (EPI == 3) {
#pragma unroll
                for (int r = 0; r < 4; r++) {
                    size_t idx = (size_t)(row0 + r) * N + col;
                    outf[idx] = resid[idx] + v[r] * gamma[col];
                }
            } else if (EPI == 4) {
                if (col < 768) {  // wave-uniform per nt
                    float sc = (col < 384) ? 0.180336880f : 1.f;  // 0.125*log2(e)
#pragma unroll
                    for (int r = 0; r < 4; r++)
                        outb[(size_t)(row0 + r) * N + col] = (bf16)(v[r] * sc);
                } else {
                    int hd = col - 768;
                    int b = row0 >> 11;
                    int n0 = row0 & 2047;
                    bf16x4 pk;
#pragma unroll
                    for (int r = 0; r < 4; r++) pk[r] = (bf16)v[r];
                    *(bf16x4*)(vtb + ((size_t)(b * 384 + hd) << 11) + n0) = pk;
                }
            } else {
#pragma unroll
                for (int r = 0; r < 4; r++)
                    outb[(size_t)(row0 + r) * N + col] = (bf16)v[r];
            }
        }
    }
}

// ---------------- fp8 MX GEMM (unit scales): C = A[M,K]f8 @ W[N,K]f8^T -------
// OUT 0: -> fp8   OUT 1: -> bf16
template <int OUT>
__global__ __launch_bounds__(256) void gemm_f8(const unsigned char* __restrict__ A,
                                               const unsigned char* __restrict__ W,
                                               bf16* __restrict__ outb,
                                               unsigned char* __restrict__ out8,
                                               int N, int K) {
    __shared__ __attribute__((aligned(16))) unsigned char As[128 * 128];
    __shared__ __attribute__((aligned(16))) unsigned char Bs[128 * 128];
    int tid = threadIdx.x;
    int wave = tid >> 6, lane = tid & 63;
    int l15 = lane & 15, quad = lane >> 4;
    int bm = blockIdx.y * 128, bn = blockIdx.x * 128;
    int wm = (wave & 1) * 64, wn = (wave >> 1) * 64;
    f32x4 acc[4][4] = {};

    for (int k0 = 0; k0 < K; k0 += 128) {
#pragma unroll
        for (int i = 0; i < 4; i++) {
            int slot = i * 256 + tid;            // 1024 chunks of 16B per tile
            int rr = slot >> 3;
            int gg = (slot & 7) ^ (rr & 7);
            GLOAD_LDS(A + (size_t)(bm + rr) * K + k0 + gg * 16,
                      (char*)As + (i * 256 + wave * 64) * 16);
            GLOAD_LDS(W + (size_t)(bn + rr) * K + k0 + gg * 16,
                      (char*)Bs + (i * 256 + wave * 64) * 16);
        }
        __syncthreads();
        i32x8 af[4], bfr[4];
#pragma unroll
        for (int mt = 0; mt < 4; mt++) {
            int rA = wm + mt * 16 + l15;
            const i32x4* p = (const i32x4*)(As + 128 * rA);
            i32x4 lo = p[(2 * quad) ^ (rA & 7)];
            i32x4 hi = p[(2 * quad + 1) ^ (rA & 7)];
#pragma unroll
            for (int j = 0; j < 4; j++) { af[mt][j] = lo[j]; af[mt][4 + j] = hi[j]; }
        }
#pragma unroll
        for (int nt = 0; nt < 4; nt++) {
            int rB = wn + nt * 16 + l15;
            const i32x4* p = (const i32x4*)(Bs + 128 * rB);
            i32x4 lo = p[(2 * quad) ^ (rB & 7)];
            i32x4 hi = p[(2 * quad + 1) ^ (rB & 7)];
#pragma unroll
            for (int j = 0; j < 4; j++) { bfr[nt][j] = lo[j]; bfr[nt][4 + j] = hi[j]; }
        }
#pragma unroll
        for (int mt = 0; mt < 4; mt++)
#pragma unroll
            for (int nt = 0; nt < 4; nt++)
                acc[mt][nt] = __builtin_amdgcn_mfma_scale_f32_16x16x128_f8f6f4(
                    af[mt], bfr[nt], acc[mt][nt], 0, 0,
                    0, 0x7f7f7f7f, 0, 0x7f7f7f7f);
        __syncthreads();
    }

#pragma unroll
    for (int mt = 0; mt < 4; mt++) {
#pragma unroll
        for (int nt = 0; nt < 4; nt++) {
            int col = bn + wn + nt * 16 + l15;
            int row0 = bm + wm + mt * 16 + quad * 4;
#pragma unroll
            for (int r = 0; r < 4; r++) {
                float v = acc[mt][nt][r];
                if (OUT == 0)
                    out8[(size_t)(row0 + r) * N + col] = (unsigned char)
                        (__builtin_amdgcn_cvt_pk_fp8_f32(v, v, 0, false) & 0xff);
                else
                    outb[(size_t)(row0 + r) * N + col] = (bf16)v;
            }
        }
    }
}

// ---------------- flash attention: 128 Q rows/block, 8 waves x 16 rows -------
// 512 threads for wave-level parallelism (latency-bound kernel).
__global__ __launch_bounds__(512, 8) void attn_kernel(const bf16* __restrict__ qkv,
                                                      const bf16* __restrict__ vtb,
                                                      bf16* __restrict__ o) {
    __shared__ __attribute__((aligned(16))) bf16 Ks[64 * 64];
    __shared__ __attribute__((aligned(16))) bf16 Vts[64 * 64];
    __shared__ __attribute__((aligned(16))) bf16 Ps[8][16][72];
    int tid = threadIdx.x, wave = tid >> 6, lane = tid & 63;
    int l15 = lane & 15, quad = lane >> 4;
    int bh = blockIdx.y;
    int b = bh / HEADS, h = bh - b * HEADS;
    int qr0 = blockIdx.x * 128 + wave * 16;
    const size_t rstr = 3 * DIM;
    const bf16* base = qkv + (size_t)b * SEQ * rstr;
    const bf16* vbase = vtb + ((size_t)bh << 17);

    // staging: one 16B chunk per thread per tile for K and V
    int rr = tid >> 3, gg = (tid & 7) ^ (rr & 7);
    const bf16* kg = base + (size_t)rr * rstr + DIM + h * 64 + gg * 8;
    const bf16* vg = vbase + ((size_t)rr << 11) + gg * 8;
    int ldsoff = tid * 16;

    // Q fragment (B-operand): row n=l15 holds Q[qr0+l15][32ks+8q+j]
    bf16x8 aq[2];
#pragma unroll
    for (int ks = 0; ks < 2; ks++)
        aq[ks] = *(const bf16x8*)(base + (size_t)(qr0 + l15) * rstr + h * 64 + ks * 32 + quad * 8);

    f32x4 oacc[4] = {};
    float lsum = 0.f;

    for (int kt = 0; kt < SEQ / 64; kt++) {
        size_t kb = (size_t)kt * 64;
        GLOAD_LDS(kg + kb * rstr, (char*)Ks + ldsoff);
        GLOAD_LDS(vg + kb, (char*)Vts + ldsoff);
        __syncthreads();

        // S^T = K Q^T ; immediately exp + pack per nt to keep liveness low
#pragma unroll
        for (int nt = 0; nt < 4; nt++) {
            int rK = nt * 16 + l15;
            f32x4 s = {};
#pragma unroll
            for (int ks = 0; ks < 2; ks++) {
                bf16x8 ak = *(const bf16x8*)((char*)Ks +
                            16 * (8 * rK + ((4 * ks + quad) ^ (rK & 7))));
                s = __builtin_amdgcn_mfma_f32_16x16x32_bf16(ak, aq[ks], s, 0, 0, 0);
            }
            bf16x4 pk;
#pragma unroll
            for (int r = 0; r < 4; r++) {
                float p = __builtin_amdgcn_exp2f(s[r]);
                lsum += p;
                pk[r] = (bf16)p;
            }
            *(bf16x4*)&Ps[wave][l15][nt * 16 + quad * 4] = pk;
        }

        // O += P V
#pragma unroll
        for (int ks = 0; ks < 2; ks++) {
            bf16x8 ap = *(const bf16x8*)&Ps[wave][l15][ks * 32 + quad * 8];
#pragma unroll
            for (int dt = 0; dt < 4; dt++) {
                int rV = dt * 16 + l15;
                bf16x8 bv = *(const bf16x8*)((char*)Vts +
                            16 * (8 * rV + ((4 * ks + quad) ^ (rV & 7))));
                oacc[dt] = __builtin_amdgcn_mfma_f32_16x16x32_bf16(ap, bv, oacc[dt], 0, 0, 0);
            }
        }
        __syncthreads();
    }

    // reduce row sums across quads (rows live at l15)
    lsum += __shfl_xor(lsum, 16, 64);
    lsum += __shfl_xor(lsum, 32, 64);
#pragma unroll
    for (int r = 0; r < 4; r++) {
        float lt = __shfl(lsum, 4 * quad + r, 64);
        float inv = 1.f / lt;
        int qrow = qr0 + quad * 4 + r;
        bf16* orow = o + ((size_t)(b * SEQ + qrow)) * DIM + h * 64;
#pragma unroll
        for (int dt = 0; dt < 4; dt++) orow[dt * 16 + l15] = (bf16)(oacc[dt][r] * inv);
    }
}

// ---------------- orchestration ----------------------------------------------
extern "C" void kernel_launch(void* const* d_in, const int* in_sizes, int n_in,
                              void* d_out, int out_size, void* d_ws, size_t ws_size,
                              hipStream_t stream) {
    const float* x      = (const float*)d_in[0];
    const float* qkv_w  = (const float*)d_in[1];
    const float* qkv_b  = (const float*)d_in[2];
    const float* proj_w = (const float*)d_in[3];
    const float* proj_b = (const float*)d_in[4];
    const float* fc1_w  = (const float*)d_in[5];
    const float* fc1_b  = (const float*)d_in[6];
    const float* eye1_w = (const float*)d_in[7];
    const float* eye2_w = (const float*)d_in[8];
    const float* fc2_w  = (const float*)d_in[9];
    const float* fc2_b  = (const float*)d_in[10];
    const float* n1w    = (const float*)d_in[11];
    const float* n1b    = (const float*)d_in[12];
    const float* n2w    = (const float*)d_in[13];
    const float* n2b    = (const float*)d_in[14];
    const float* ls1    = (const float*)d_in[15];
    const float* ls2    = (const float*)d_in[16];
    float* out = (float*)d_out;

    char* w = (char*)d_ws;
    size_t off = 0;
    bf16* wbf = (bf16*)(w + off); off += (size_t)NW_BF * 2;
    bf16* wqkv  = wbf;
    bf16* wproj = wqkv + NW_QKV;
    bf16* wfc1  = wproj + NW_PROJ;
    bf16* wfc2  = wfc1 + NW_FC1;
    unsigned char* weye8 = (unsigned char*)(w + off); off += 2 * (size_t)NW_EYE;
    bf16* hbuf  = (bf16*)(w + off); off += (size_t)TOKENS * DIM * 2;
    bf16* qkvb  = (bf16*)(w + off); off += (size_t)TOKENS * 3 * DIM * 2;
    bf16* vtb   = (bf16*)(w + off); off += (size_t)TOKENS * DIM * 2;
    bf16* obuf  = (bf16*)(w + off); off += (size_t)TOKENS * DIM * 2;
    bf16* abuf  = (bf16*)(w + off); off += (size_t)TOKENS * HIDDEN * 2;
    float* x1   = (float*)(w + off); off += (size_t)TOKENS * DIM * 4;
    // fp8 overlays on dead regions (stream-ordered reuse):
    unsigned char* abuf8 = (unsigned char*)qkvb;  // fc1 out; qkvb dead after attn
    unsigned char* tbuf8 = (unsigned char*)vtb;   // eye1 out; vtb+obuf dead after proj

    convert_weights<<<1728, 256, 0, stream>>>(qkv_w, proj_w, fc1_w, fc2_w, wbf);
    convert_eyes_f8<<<4096, 256, 0, stream>>>(eye1_w, eye2_w, weye8);

    ln_kernel<<<TOKENS / 4, 256, 0, stream>>>(x, n1w, n1b, hbuf);

    gemm_bt<4><<<dim3(1152 / 128, TOKENS / 128), 256, 0, stream>>>(
        hbuf, wqkv, qkv_b, qkvb, nullptr, nullptr, nullptr, vtb, nullptr, 1152, 384);

    attn_kernel<<<dim3(SEQ / 128, BATCH * HEADS), 512, 0, stream>>>(qkvb, vtb, obuf);

    gemm_bt<3><<<dim3(384 / 128, TOKENS / 128), 256, 0, stream>>>(
        obuf, wproj, proj_b, nullptr, x1, x, ls1, nullptr, nullptr, 384, 384);

    ln_kernel<<<TOKENS / 4, 256, 0, stream>>>(x1, n2w, n2b, hbuf);

    gemm_bt<2><<<dim3(1536 / 128, TOKENS / 128), 256, 0, stream>>>(
        hbuf, wfc1, fc1_b, nullptr, nullptr, nullptr, nullptr, nullptr, abuf8, 1536, 384);

    gemm_f8<0><<<dim3(1536 / 128, TOKENS / 128), 256, 0, stream>>>(
        abuf8, weye8, nullptr, tbuf8, 1536, 1536);

    gemm_f8<1><<<dim3(1536 / 128, TOKENS / 128), 256, 0, stream>>>(
        tbuf8, weye8 + NW_EYE, abuf, nullptr, 1536, 1536);

    gemm_bt<3><<<dim3(384 / 128, TOKENS / 128), 256, 0, stream>>>(
        abuf, wfc2, fc2_b, nullptr, out, x1, ls2, nullptr, nullptr, 384, 1536);
}

// Round 7
// 389.620 us; speedup vs baseline: 1.8385x; 1.0502x over previous
//
#include <hip/hip_runtime.h>
#include <math.h>

#define DIM 384
#define HEADS 6
#define HEAD_DIM 64
#define HIDDEN 1536
#define BATCH 8
#define SEQ 2048
#define TOKENS (BATCH * SEQ)

typedef __bf16 bf16;
typedef __bf16 bf16x8 __attribute__((ext_vector_type(8)));
typedef __bf16 bf16x4 __attribute__((ext_vector_type(4)));
typedef float f32x4 __attribute__((ext_vector_type(4)));
typedef int i32x4 __attribute__((ext_vector_type(4)));
typedef int i32x8 __attribute__((ext_vector_type(8)));

#define GLOAD_LDS(gp, lp)                                                      \
    __builtin_amdgcn_global_load_lds(                                          \
        (const __attribute__((address_space(1))) void*)(gp),                   \
        (__attribute__((address_space(3))) void*)(lp), 16, 0, 0)

__device__ __forceinline__ unsigned char to_fp8(float v) {
    return (unsigned char)(__builtin_amdgcn_cvt_pk_fp8_f32(v, v, 0, false) & 0xff);
}

// ---------------- weight conversion: ALL weights fp32 -> fp8 -----------------
#define NW_QKV  (1152 * 384)
#define NW_PROJ (384 * 384)
#define NW_FC1  (1536 * 384)
#define NW_EYE  (1536 * 1536)
#define NW_FC2  (384 * 1536)
#define NW_ALL  (NW_QKV + NW_PROJ + NW_FC1 + 2 * NW_EYE + NW_FC2)

__global__ void convert_w8(const float* __restrict__ qkv, const float* __restrict__ proj,
                           const float* __restrict__ fc1, const float* __restrict__ e1,
                           const float* __restrict__ e2, const float* __restrict__ fc2,
                           unsigned char* __restrict__ dst) {
    int q4 = blockIdx.x * 256 + threadIdx.x;
    int stride = gridDim.x * 256;
    for (; q4 < NW_ALL / 4; q4 += stride) {
        int i = q4 * 4;
        int j = i;
        const float* src;
        if (j < NW_QKV) src = qkv;
        else if ((j -= NW_QKV) < NW_PROJ) src = proj;
        else if ((j -= NW_PROJ) < NW_FC1) src = fc1;
        else if ((j -= NW_FC1) < NW_EYE) src = e1;
        else if ((j -= NW_EYE) < NW_EYE) src = e2;
        else { j -= NW_EYE; src = fc2; }
        float4 v = *(const float4*)(src + j);
        int p = __builtin_amdgcn_cvt_pk_fp8_f32(v.x, v.y, 0, false);
        p = __builtin_amdgcn_cvt_pk_fp8_f32(v.z, v.w, p, true);
        *(int*)(dst + i) = p;
    }
}

// ---------------- LayerNorm: fp32 in -> fp8 out, one wave per token ----------
__global__ __launch_bounds__(256) void ln_kernel(const float* __restrict__ x,
                                                 const float* __restrict__ w,
                                                 const float* __restrict__ b,
                                                 unsigned char* __restrict__ out) {
    int wave = threadIdx.x >> 6;
    int lane = threadIdx.x & 63;
    int t = blockIdx.x * 4 + wave;
    const float* xr = x + (size_t)t * DIM;
    float v[6];
    float s = 0.f;
#pragma unroll
    for (int i = 0; i < 6; i++) { v[i] = xr[lane + 64 * i]; s += v[i]; }
#pragma unroll
    for (int m = 1; m < 64; m <<= 1) s += __shfl_xor(s, m, 64);
    float mu = s * (1.f / DIM);
    float q = 0.f;
#pragma unroll
    for (int i = 0; i < 6; i++) { float d = v[i] - mu; q += d * d; }
#pragma unroll
    for (int m = 1; m < 64; m <<= 1) q += __shfl_xor(q, m, 64);
    float rstd = rsqrtf(q * (1.f / DIM) + 1e-5f);
    unsigned char* orow = out + (size_t)t * DIM;
#pragma unroll
    for (int i = 0; i < 6; i++) {
        int c = lane + 64 * i;
        orow[c] = to_fp8((v[i] - mu) * rstd * w[c] + b[c]);
    }
}

// ---------------- fp8 MX GEMM (unit scales): C = A[M,K]f8 @ W[N,K]f8^T -------
// EPI 0: plain -> fp8
// EPI 2: +bias, exact GELU -> fp8
// EPI 3: +bias, out_f32 = resid + v*gamma
// EPI 4: qkv: +bias; Q cols scaled -> bf16 qkvb; K -> bf16; V -> bf16 vtb^T
template <int EPI>
__global__ __launch_bounds__(256) void gemm_f8(const unsigned char* __restrict__ A,
                                               const unsigned char* __restrict__ W,
                                               const float* __restrict__ bias,
                                               bf16* __restrict__ outb,
                                               float* __restrict__ outf,
                                               const float* __restrict__ resid,
                                               const float* __restrict__ gamma,
                                               bf16* __restrict__ vtb,
                                               unsigned char* __restrict__ out8,
                                               int N, int K) {
    __shared__ __attribute__((aligned(16))) unsigned char As[128 * 128];
    __shared__ __attribute__((aligned(16))) unsigned char Bs[128 * 128];
    int tid = threadIdx.x;
    int wave = tid >> 6, lane = tid & 63;
    int l15 = lane & 15, quad = lane >> 4;
    int bm = blockIdx.y * 128, bn = blockIdx.x * 128;
    int wm = (wave & 1) * 64, wn = (wave >> 1) * 64;
    f32x4 acc[4][4] = {};

    for (int k0 = 0; k0 < K; k0 += 128) {
#pragma unroll
        for (int i = 0; i < 4; i++) {
            int slot = i * 256 + tid;            // 1024 chunks of 16B per tile
            int rr = slot >> 3;
            int gg = (slot & 7) ^ (rr & 7);
            GLOAD_LDS(A + (size_t)(bm + rr) * K + k0 + gg * 16,
                      (char*)As + (i * 256 + wave * 64) * 16);
            GLOAD_LDS(W + (size_t)(bn + rr) * K + k0 + gg * 16,
                      (char*)Bs + (i * 256 + wave * 64) * 16);
        }
        __syncthreads();
        i32x8 af[4], bfr[4];
#pragma unroll
        for (int mt = 0; mt < 4; mt++) {
            int rA = wm + mt * 16 + l15;
            const i32x4* p = (const i32x4*)(As + 128 * rA);
            i32x4 lo = p[(2 * quad) ^ (rA & 7)];
            i32x4 hi = p[(2 * quad + 1) ^ (rA & 7)];
#pragma unroll
            for (int j = 0; j < 4; j++) { af[mt][j] = lo[j]; af[mt][4 + j] = hi[j]; }
        }
#pragma unroll
        for (int nt = 0; nt < 4; nt++) {
            int rB = wn + nt * 16 + l15;
            const i32x4* p = (const i32x4*)(Bs + 128 * rB);
            i32x4 lo = p[(2 * quad) ^ (rB & 7)];
            i32x4 hi = p[(2 * quad + 1) ^ (rB & 7)];
#pragma unroll
            for (int j = 0; j < 4; j++) { bfr[nt][j] = lo[j]; bfr[nt][4 + j] = hi[j]; }
        }
#pragma unroll
        for (int mt = 0; mt < 4; mt++)
#pragma unroll
            for (int nt = 0; nt < 4; nt++)
                acc[mt][nt] = __builtin_amdgcn_mfma_scale_f32_16x16x128_f8f6f4(
                    af[mt], bfr[nt], acc[mt][nt], 0, 0,
                    0, 0x7f7f7f7f, 0, 0x7f7f7f7f);
        __syncthreads();
    }

#pragma unroll
    for (int mt = 0; mt < 4; mt++) {
#pragma unroll
        for (int nt = 0; nt < 4; nt++) {
            int col = bn + wn + nt * 16 + l15;
            int row0 = bm + wm + mt * 16 + quad * 4;
            float v[4];
#pragma unroll
            for (int r = 0; r < 4; r++) {
                v[r] = acc[mt][nt][r];
                if (EPI >= 2) v[r] += bias[col];
                if (EPI == 2) v[r] = 0.5f * v[r] * (1.f + erff(v[r] * 0.70710678118654752f));
            }
            if (EPI == 3) {
#pragma unroll
                for (int r = 0; r < 4; r++) {
                    size_t idx = (size_t)(row0 + r) * N + col;
                    outf[idx] = resid[idx] + v[r] * gamma[col];
                }
            } else if (EPI == 4) {
                if (col < 768) {  // wave-uniform per nt (boundary multiple of 16)
                    float sc = (col < 384) ? 0.180336880f : 1.f;  // 0.125*log2(e)
#pragma unroll
                    for (int r = 0; r < 4; r++)
                        outb[(size_t)(row0 + r) * N + col] = (bf16)(v[r] * sc);
                } else {
                    int hd = col - 768;
                    int b = row0 >> 11;
                    int n0 = row0 & 2047;
                    bf16x4 pk;
#pragma unroll
                    for (int r = 0; r < 4; r++) pk[r] = (bf16)v[r];
                    *(bf16x4*)(vtb + ((size_t)(b * 384 + hd) << 11) + n0) = pk;
                }
            } else {
#pragma unroll
                for (int r = 0; r < 4; r++)
                    out8[(size_t)(row0 + r) * N + col] = to_fp8(v[r]);
            }
        }
    }
}

// ---------------- flash attention: 128 Q rows/block, 8 waves x 16 rows -------
// bf16 QK^T / PV core; writes fp8 output for the fp8 proj GEMM.
__global__ __launch_bounds__(512, 8) void attn_kernel(const bf16* __restrict__ qkv,
                                                      const bf16* __restrict__ vtb,
                                                      unsigned char* __restrict__ o) {
    __shared__ __attribute__((aligned(16))) bf16 Ks[64 * 64];
    __shared__ __attribute__((aligned(16))) bf16 Vts[64 * 64];
    __shared__ __attribute__((aligned(16))) bf16 Ps[8][16][72];
    int tid = threadIdx.x, wave = tid >> 6, lane = tid & 63;
    int l15 = lane & 15, quad = lane >> 4;
    int bh = blockIdx.y;
    int b = bh / HEADS, h = bh - b * HEADS;
    int qr0 = blockIdx.x * 128 + wave * 16;
    const size_t rstr = 3 * DIM;
    const bf16* base = qkv + (size_t)b * SEQ * rstr;
    const bf16* vbase = vtb + ((size_t)bh << 17);

    int rr = tid >> 3, gg = (tid & 7) ^ (rr & 7);
    const bf16* kg = base + (size_t)rr * rstr + DIM + h * 64 + gg * 8;
    const bf16* vg = vbase + ((size_t)rr << 11) + gg * 8;
    int ldsoff = tid * 16;

    bf16x8 aq[2];
#pragma unroll
    for (int ks = 0; ks < 2; ks++)
        aq[ks] = *(const bf16x8*)(base + (size_t)(qr0 + l15) * rstr + h * 64 + ks * 32 + quad * 8);

    f32x4 oacc[4] = {};
    float lsum = 0.f;

    for (int kt = 0; kt < SEQ / 64; kt++) {
        size_t kb = (size_t)kt * 64;
        GLOAD_LDS(kg + kb * rstr, (char*)Ks + ldsoff);
        GLOAD_LDS(vg + kb, (char*)Vts + ldsoff);
        __syncthreads();

#pragma unroll
        for (int nt = 0; nt < 4; nt++) {
            int rK = nt * 16 + l15;
            f32x4 s = {};
#pragma unroll
            for (int ks = 0; ks < 2; ks++) {
                bf16x8 ak = *(const bf16x8*)((char*)Ks +
                            16 * (8 * rK + ((4 * ks + quad) ^ (rK & 7))));
                s = __builtin_amdgcn_mfma_f32_16x16x32_bf16(ak, aq[ks], s, 0, 0, 0);
            }
            bf16x4 pk;
#pragma unroll
            for (int r = 0; r < 4; r++) {
                float p = __builtin_amdgcn_exp2f(s[r]);
                lsum += p;
                pk[r] = (bf16)p;
            }
            *(bf16x4*)&Ps[wave][l15][nt * 16 + quad * 4] = pk;
        }

#pragma unroll
        for (int ks = 0; ks < 2; ks++) {
            bf16x8 ap = *(const bf16x8*)&Ps[wave][l15][ks * 32 + quad * 8];
#pragma unroll
            for (int dt = 0; dt < 4; dt++) {
                int rV = dt * 16 + l15;
                bf16x8 bv = *(const bf16x8*)((char*)Vts +
                            16 * (8 * rV + ((4 * ks + quad) ^ (rV & 7))));
                oacc[dt] = __builtin_amdgcn_mfma_f32_16x16x32_bf16(ap, bv, oacc[dt], 0, 0, 0);
            }
        }
        __syncthreads();
    }

    lsum += __shfl_xor(lsum, 16, 64);
    lsum += __shfl_xor(lsum, 32, 64);
#pragma unroll
    for (int r = 0; r < 4; r++) {
        float lt = __shfl(lsum, 4 * quad + r, 64);
        float inv = 1.f / lt;
        int qrow = qr0 + quad * 4 + r;
        unsigned char* orow = o + ((size_t)(b * SEQ + qrow)) * DIM + h * 64;
#pragma unroll
        for (int dt = 0; dt < 4; dt++) orow[dt * 16 + l15] = to_fp8(oacc[dt][r] * inv);
    }
}

// ---------------- orchestration ----------------------------------------------
extern "C" void kernel_launch(void* const* d_in, const int* in_sizes, int n_in,
                              void* d_out, int out_size, void* d_ws, size_t ws_size,
                              hipStream_t stream) {
    const float* x      = (const float*)d_in[0];
    const float* qkv_w  = (const float*)d_in[1];
    const float* qkv_b  = (const float*)d_in[2];
    const float* proj_w = (const float*)d_in[3];
    const float* proj_b = (const float*)d_in[4];
    const float* fc1_w  = (const float*)d_in[5];
    const float* fc1_b  = (const float*)d_in[6];
    const float* eye1_w = (const float*)d_in[7];
    const float* eye2_w = (const float*)d_in[8];
    const float* fc2_w  = (const float*)d_in[9];
    const float* fc2_b  = (const float*)d_in[10];
    const float* n1w    = (const float*)d_in[11];
    const float* n1b    = (const float*)d_in[12];
    const float* n2w    = (const float*)d_in[13];
    const float* n2b    = (const float*)d_in[14];
    const float* ls1    = (const float*)d_in[15];
    const float* ls2    = (const float*)d_in[16];
    float* out = (float*)d_out;

    char* w = (char*)d_ws;
    size_t off = 0;
    unsigned char* w8 = (unsigned char*)(w + off); off += (size_t)NW_ALL;
    unsigned char* wqkv8  = w8;
    unsigned char* wproj8 = wqkv8 + NW_QKV;
    unsigned char* wfc18  = wproj8 + NW_PROJ;
    unsigned char* weye18 = wfc18 + NW_FC1;
    unsigned char* weye28 = weye18 + NW_EYE;
    unsigned char* wfc28  = weye28 + NW_EYE;
    unsigned char* hbuf8 = (unsigned char*)(w + off); off += (size_t)TOKENS * DIM;
    bf16* qkvb  = (bf16*)(w + off); off += (size_t)TOKENS * 3 * DIM * 2;
    bf16* vtb   = (bf16*)(w + off); off += (size_t)TOKENS * DIM * 2;
    unsigned char* obuf8 = (unsigned char*)(w + off); off += (size_t)TOKENS * DIM;
    unsigned char* abuf8 = (unsigned char*)(w + off); off += (size_t)TOKENS * HIDDEN;
    unsigned char* tbuf8 = (unsigned char*)(w + off); off += (size_t)TOKENS * HIDDEN;
    float* x1   = (float*)(w + off); off += (size_t)TOKENS * DIM * 4;

    convert_w8<<<4096, 256, 0, stream>>>(qkv_w, proj_w, fc1_w, eye1_w, eye2_w, fc2_w, w8);

    ln_kernel<<<TOKENS / 4, 256, 0, stream>>>(x, n1w, n1b, hbuf8);

    gemm_f8<4><<<dim3(1152 / 128, TOKENS / 128), 256, 0, stream>>>(
        hbuf8, wqkv8, qkv_b, qkvb, nullptr, nullptr, nullptr, vtb, nullptr, 1152, 384);

    attn_kernel<<<dim3(SEQ / 128, BATCH * HEADS), 512, 0, stream>>>(qkvb, vtb, obuf8);

    gemm_f8<3><<<dim3(384 / 128, TOKENS / 128), 256, 0, stream>>>(
        obuf8, wproj8, proj_b, nullptr, x1, x, ls1, nullptr, nullptr, 384, 384);

    ln_kernel<<<TOKENS / 4, 256, 0, stream>>>(x1, n2w, n2b, hbuf8);

    gemm_f8<2><<<dim3(1536 / 128, TOKENS / 128), 256, 0, stream>>>(
        hbuf8, wfc18, fc1_b, nullptr, nullptr, nullptr, nullptr, nullptr, abuf8, 1536, 384);

    gemm_f8<0><<<dim3(1536 / 128, TOKENS / 128), 256, 0, stream>>>(
        abuf8, weye18, nullptr, nullptr, nullptr, nullptr, nullptr, nullptr, tbuf8, 1536, 1536);

    gemm_f8<0><<<dim3(1536 / 128, TOKENS / 128), 256, 0, stream>>>(
        tbuf8, weye28, nullptr, nullptr, nullptr, nullptr, nullptr, nullptr, abuf8, 1536, 1536);

    gemm_f8<3><<<dim3(384 / 128, TOKENS / 128), 256, 0, stream>>>(
        abuf8, wfc28, fc2_b, nullptr, out, x1, ls2, nullptr, nullptr, 384, 1536);
}

// Round 9
// 354.267 us; speedup vs baseline: 2.0220x; 1.0998x over previous
//
#include <hip/hip_runtime.h>
#include <math.h>

#define DIM 384
#define HEADS 6
#define HEAD_DIM 64
#define HIDDEN 1536
#define BATCH 8
#define SEQ 2048
#define TOKENS (BATCH * SEQ)

typedef __bf16 bf16;
typedef float f32x4 __attribute__((ext_vector_type(4)));
typedef float f32x16 __attribute__((ext_vector_type(16)));
typedef int i32x4 __attribute__((ext_vector_type(4)));
typedef int i32x8 __attribute__((ext_vector_type(8)));

#define GLOAD_LDS(gp, lp)                                                      \
    __builtin_amdgcn_global_load_lds(                                          \
        (const __attribute__((address_space(1))) void*)(gp),                   \
        (__attribute__((address_space(3))) void*)(lp), 16, 0, 0)

__device__ __forceinline__ unsigned char to_fp8(float v) {
    return (unsigned char)(__builtin_amdgcn_cvt_pk_fp8_f32(v, v, 0, false) & 0xff);
}

__device__ __forceinline__ i32x8 pack8(i32x4 lo, i32x4 hi) {
    i32x8 r;
#pragma unroll
    for (int j = 0; j < 4; j++) { r[j] = lo[j]; r[4 + j] = hi[j]; }
    return r;
}

// ---------------- weight conversion: ALL weights fp32 -> fp8 -----------------
#define NW_QKV  (1152 * 384)
#define NW_PROJ (384 * 384)
#define NW_FC1  (1536 * 384)
#define NW_EYE  (1536 * 1536)
#define NW_FC2  (384 * 1536)
#define NW_ALL  (NW_QKV + NW_PROJ + NW_FC1 + 2 * NW_EYE + NW_FC2)

__global__ void convert_w8(const float* __restrict__ qkv, const float* __restrict__ proj,
                           const float* __restrict__ fc1, const float* __restrict__ e1,
                           const float* __restrict__ e2, const float* __restrict__ fc2,
                           unsigned char* __restrict__ dst) {
    int q4 = blockIdx.x * 256 + threadIdx.x;
    int stride = gridDim.x * 256;
    for (; q4 < NW_ALL / 4; q4 += stride) {
        int i = q4 * 4;
        int j = i;
        const float* src;
        if (j < NW_QKV) src = qkv;
        else if ((j -= NW_QKV) < NW_PROJ) src = proj;
        else if ((j -= NW_PROJ) < NW_FC1) src = fc1;
        else if ((j -= NW_FC1) < NW_EYE) src = e1;
        else if ((j -= NW_EYE) < NW_EYE) src = e2;
        else { j -= NW_EYE; src = fc2; }
        float4 v = *(const float4*)(src + j);
        int p = __builtin_amdgcn_cvt_pk_fp8_f32(v.x, v.y, 0, false);
        p = __builtin_amdgcn_cvt_pk_fp8_f32(v.z, v.w, p, true);
        *(int*)(dst + i) = p;
    }
}

// ---------------- LayerNorm: fp32 in -> fp8 out, one wave per token ----------
__global__ __launch_bounds__(256) void ln_kernel(const float* __restrict__ x,
                                                 const float* __restrict__ w,
                                                 const float* __restrict__ b,
                                                 unsigned char* __restrict__ out) {
    int wave = threadIdx.x >> 6;
    int lane = threadIdx.x & 63;
    int t = blockIdx.x * 4 + wave;
    const float* xr = x + (size_t)t * DIM;
    float v[6];
    float s = 0.f;
#pragma unroll
    for (int i = 0; i < 6; i++) { v[i] = xr[lane + 64 * i]; s += v[i]; }
#pragma unroll
    for (int m = 1; m < 64; m <<= 1) s += __shfl_xor(s, m, 64);
    float mu = s * (1.f / DIM);
    float q = 0.f;
#pragma unroll
    for (int i = 0; i < 6; i++) { float d = v[i] - mu; q += d * d; }
#pragma unroll
    for (int m = 1; m < 64; m <<= 1) q += __shfl_xor(q, m, 64);
    float rstd = rsqrtf(q * (1.f / DIM) + 1e-5f);
    unsigned char* orow = out + (size_t)t * DIM;
#pragma unroll
    for (int i = 0; i < 6; i++) {
        int c = lane + 64 * i;
        orow[c] = to_fp8((v[i] - mu) * rstd * w[c] + b[c]);
    }
}

// ---------------- fp8 MX GEMM (unit scales): C = A[M,K]f8 @ W[N,K]f8^T -------
// EPI 0: plain -> fp8
// EPI 2: +bias, exact GELU -> fp8
// EPI 3: +bias, out_f32 = resid + v*gamma
// EPI 4: qkv: +bias; Q (scaled) + K -> fp8 qk8[tok][768]; V -> fp8 vtb8^T
template <int EPI>
__global__ __launch_bounds__(256) void gemm_f8(const unsigned char* __restrict__ A,
                                               const unsigned char* __restrict__ W,
                                               const float* __restrict__ bias,
                                               float* __restrict__ outf,
                                               const float* __restrict__ resid,
                                               const float* __restrict__ gamma,
                                               unsigned char* __restrict__ vtb8,
                                               unsigned char* __restrict__ out8,
                                               int N, int K) {
    __shared__ __attribute__((aligned(16))) unsigned char As[128 * 128];
    __shared__ __attribute__((aligned(16))) unsigned char Bs[128 * 128];
    int tid = threadIdx.x;
    int wave = tid >> 6, lane = tid & 63;
    int l15 = lane & 15, quad = lane >> 4;
    int bm = blockIdx.y * 128, bn = blockIdx.x * 128;
    int wm = (wave & 1) * 64, wn = (wave >> 1) * 64;
    f32x4 acc[4][4] = {};

    for (int k0 = 0; k0 < K; k0 += 128) {
#pragma unroll
        for (int i = 0; i < 4; i++) {
            int slot = i * 256 + tid;            // 1024 chunks of 16B per tile
            int rr = slot >> 3;
            int gg = (slot & 7) ^ (rr & 7);
            GLOAD_LDS(A + (size_t)(bm + rr) * K + k0 + gg * 16,
                      (char*)As + (i * 256 + wave * 64) * 16);
            GLOAD_LDS(W + (size_t)(bn + rr) * K + k0 + gg * 16,
                      (char*)Bs + (i * 256 + wave * 64) * 16);
        }
        __syncthreads();
        i32x8 af[4], bfr[4];
#pragma unroll
        for (int mt = 0; mt < 4; mt++) {
            int rA = wm + mt * 16 + l15;
            const i32x4* p = (const i32x4*)(As + 128 * rA);
            af[mt] = pack8(p[(2 * quad) ^ (rA & 7)], p[(2 * quad + 1) ^ (rA & 7)]);
        }
#pragma unroll
        for (int nt = 0; nt < 4; nt++) {
            int rB = wn + nt * 16 + l15;
            const i32x4* p = (const i32x4*)(Bs + 128 * rB);
            bfr[nt] = pack8(p[(2 * quad) ^ (rB & 7)], p[(2 * quad + 1) ^ (rB & 7)]);
        }
#pragma unroll
        for (int mt = 0; mt < 4; mt++)
#pragma unroll
            for (int nt = 0; nt < 4; nt++)
                acc[mt][nt] = __builtin_amdgcn_mfma_scale_f32_16x16x128_f8f6f4(
                    af[mt], bfr[nt], acc[mt][nt], 0, 0,
                    0, 0x7f7f7f7f, 0, 0x7f7f7f7f);
        __syncthreads();
    }

#pragma unroll
    for (int mt = 0; mt < 4; mt++) {
#pragma unroll
        for (int nt = 0; nt < 4; nt++) {
            int col = bn + wn + nt * 16 + l15;
            int row0 = bm + wm + mt * 16 + quad * 4;
            float v[4];
#pragma unroll
            for (int r = 0; r < 4; r++) {
                v[r] = acc[mt][nt][r];
                if (EPI >= 2) v[r] += bias[col];
                if (EPI == 2) v[r] = 0.5f * v[r] * (1.f + erff(v[r] * 0.70710678118654752f));
            }
            if (EPI == 3) {
#pragma unroll
                for (int r = 0; r < 4; r++) {
                    size_t idx = (size_t)(row0 + r) * N + col;
                    outf[idx] = resid[idx] + v[r] * gamma[col];
                }
            } else if (EPI == 4) {
                if (col < 768) {  // wave-uniform per nt (boundary multiple of 16)
                    float sc = (col < 384) ? 0.180336880f : 1.f;  // 0.125*log2(e)
#pragma unroll
                    for (int r = 0; r < 4; r++)
                        out8[(size_t)(row0 + r) * 768 + col] = to_fp8(v[r] * sc);
                } else {
                    int hd = col - 768;
                    int b = row0 >> 11;
                    int n0 = row0 & 2047;
                    int p = __builtin_amdgcn_cvt_pk_fp8_f32(v[0], v[1], 0, false);
                    p = __builtin_amdgcn_cvt_pk_fp8_f32(v[2], v[3], p, true);
                    *(int*)(vtb8 + ((size_t)(b * 384 + hd) << 11) + n0) = p;
                }
            } else {
#pragma unroll
                for (int r = 0; r < 4; r++)
                    out8[(size_t)(row0 + r) * N + col] = to_fp8(v[r]);
            }
        }
    }
}

// ---------------- flash attention, fp8 32x32x64 core -------------------------
// 128 Q rows/block, 4 waves x 32 rows. Q pre-scaled by 0.125*log2(e).
// qk8: [token][768] (q fp8 cols 0..383, k fp8 cols 384..767); vtb8: V^T fp8.
__global__ __launch_bounds__(256, 3) void attn_kernel(const unsigned char* __restrict__ qk8,
                                                      const unsigned char* __restrict__ vtb8,
                                                      unsigned char* __restrict__ o) {
    __shared__ __attribute__((aligned(16))) unsigned char Ks[64 * 64];
    __shared__ __attribute__((aligned(16))) unsigned char Vts[64 * 64];
    __shared__ __attribute__((aligned(16))) unsigned char Ps[4][32 * 80];  // 80B pad
    int tid = threadIdx.x, wave = tid >> 6, lane = tid & 63;
    int l31 = lane & 31, h = lane >> 5;
    int bh = blockIdx.y;
    int b = bh / HEADS, hh = bh - b * HEADS;
    int qr0 = blockIdx.x * 128 + wave * 32;
    const unsigned char* base = qk8 + (size_t)b * SEQ * 768;
    const unsigned char* vbase = vtb8 + ((size_t)bh << 17);  // bh*64*2048

    // staging: thread t fills LDS slot t (16B); global slot XOR-swizzled so
    // LDS[row][s] holds src[row][s ^ (row&3)]
    int rr = tid >> 2, ss = tid & 3;
    const unsigned char* kg = base + (size_t)rr * 768 + 384 + hh * 64 + 16 * (ss ^ (rr & 3));
    const unsigned char* vg = vbase + ((size_t)rr << 11) + 16 * (ss ^ (rr & 3));
    int ldsoff = tid * 16;

    // Q B-frag: lane n=l31 holds Q[qr0+l31][32h + j], j=0..31 (32B contiguous)
    i32x8 aq = *(const i32x8*)(base + (size_t)(qr0 + l31) * 768 + hh * 64 + 32 * h);

    f32x16 oa0 = {}, oa1 = {};
    float lsum = 0.f;

    for (int kt = 0; kt < SEQ / 64; kt++) {
        GLOAD_LDS(kg + (size_t)kt * 64 * 768, (char*)Ks + ldsoff);
        GLOAD_LDS(vg + kt * 64, (char*)Vts + ldsoff);
        __syncthreads();

        // S^T = K Q^T (two 32-token halves); exp2 + pack fp8 P immediately
#pragma unroll
        for (int mi = 0; mi < 2; mi++) {
            int rK = 32 * mi + l31;
            const i32x4* kp = (const i32x4*)(Ks + rK * 64);
            i32x8 ak = pack8(kp[(2 * h + 0) ^ (l31 & 3)], kp[(2 * h + 1) ^ (l31 & 3)]);
            f32x16 s = {};
            s = __builtin_amdgcn_mfma_scale_f32_32x32x64_f8f6f4(
                ak, aq, s, 0, 0, 0, 0x7f7f7f7f, 0, 0x7f7f7f7f);
#pragma unroll
            for (int g = 0; g < 4; g++) {
                float p0 = __builtin_amdgcn_exp2f(s[4 * g + 0]);
                float p1 = __builtin_amdgcn_exp2f(s[4 * g + 1]);
                float p2 = __builtin_amdgcn_exp2f(s[4 * g + 2]);
                float p3 = __builtin_amdgcn_exp2f(s[4 * g + 3]);
                lsum += (p0 + p1) + (p2 + p3);
                int pk = __builtin_amdgcn_cvt_pk_fp8_f32(p0, p1, 0, false);
                pk = __builtin_amdgcn_cvt_pk_fp8_f32(p2, p3, pk, true);
                // tokens 32*mi + 8*g + 4*h + (0..3), row q = l31
                *(int*)&Ps[wave][l31 * 80 + 32 * mi + 8 * g + 4 * h] = pk;
            }
        }

        // O += P V : A = P rows (q=l31, tokens 32h..), B = V^T rows (d)
        {
            const i32x4* pp = (const i32x4*)&Ps[wave][l31 * 80 + 32 * h];
            i32x8 ap = pack8(pp[0], pp[1]);
            const i32x4* vp0 = (const i32x4*)(Vts + l31 * 64);
            i32x8 bv0 = pack8(vp0[(2 * h + 0) ^ (l31 & 3)], vp0[(2 * h + 1) ^ (l31 & 3)]);
            oa0 = __builtin_amdgcn_mfma_scale_f32_32x32x64_f8f6f4(
                ap, bv0, oa0, 0, 0, 0, 0x7f7f7f7f, 0, 0x7f7f7f7f);
            const i32x4* vp1 = (const i32x4*)(Vts + (32 + l31) * 64);
            i32x8 bv1 = pack8(vp1[(2 * h + 0) ^ (l31 & 3)], vp1[(2 * h + 1) ^ (l31 & 3)]);
            oa1 = __builtin_amdgcn_mfma_scale_f32_32x32x64_f8f6f4(
                ap, bv1, oa1, 0, 0, 0, 0x7f7f7f7f, 0, 0x7f7f7f7f);
        }
        __syncthreads();
    }

    // combine the two half-token partial sums for each q (lanes l and l^32)
    lsum += __shfl_xor(lsum, 32, 64);

    // O frag: col = d = l31 (+32 for oa1), row q = (r&3)+8*(r>>2)+4h
#pragma unroll
    for (int g = 0; g < 4; g++) {
#pragma unroll
        for (int r4 = 0; r4 < 4; r4++) {
            int qloc = r4 + 8 * g + 4 * h;
            float inv = 1.f / __shfl(lsum, qloc, 64);
            int r = 4 * g + r4;
            unsigned char* orow = o + ((size_t)(b * SEQ + qr0 + qloc)) * DIM + hh * 64;
            orow[l31]      = to_fp8(oa0[r] * inv);
            orow[32 + l31] = to_fp8(oa1[r] * inv);
        }
    }
}

// ---------------- orchestration ----------------------------------------------
extern "C" void kernel_launch(void* const* d_in, const int* in_sizes, int n_in,
                              void* d_out, int out_size, void* d_ws, size_t ws_size,
                              hipStream_t stream) {
    const float* x      = (const float*)d_in[0];
    const float* qkv_w  = (const float*)d_in[1];
    const float* qkv_b  = (const float*)d_in[2];
    const float* proj_w = (const float*)d_in[3];
    const float* proj_b = (const float*)d_in[4];
    const float* fc1_w  = (const float*)d_in[5];
    const float* fc1_b  = (const float*)d_in[6];
    const float* eye1_w = (const float*)d_in[7];
    const float* eye2_w = (const float*)d_in[8];
    const float* fc2_w  = (const float*)d_in[9];
    const float* fc2_b  = (const float*)d_in[10];
    const float* n1w    = (const float*)d_in[11];
    const float* n1b    = (const float*)d_in[12];
    const float* n2w    = (const float*)d_in[13];
    const float* n2b    = (const float*)d_in[14];
    const float* ls1    = (const float*)d_in[15];
    const float* ls2    = (const float*)d_in[16];
    float* out = (float*)d_out;

    char* w = (char*)d_ws;
    size_t off = 0;
    unsigned char* w8 = (unsigned char*)(w + off); off += (size_t)NW_ALL;
    unsigned char* wqkv8  = w8;
    unsigned char* wproj8 = wqkv8 + NW_QKV;
    unsigned char* wfc18  = wproj8 + NW_PROJ;
    unsigned char* weye18 = wfc18 + NW_FC1;
    unsigned char* weye28 = weye18 + NW_EYE;
    unsigned char* wfc28  = weye28 + NW_EYE;
    unsigned char* hbuf8 = (unsigned char*)(w + off); off += (size_t)TOKENS * DIM;
    unsigned char* qk8   = (unsigned char*)(w + off); off += (size_t)TOKENS * 768;
    unsigned char* vtb8  = (unsigned char*)(w + off); off += (size_t)TOKENS * DIM;
    unsigned char* obuf8 = (unsigned char*)(w + off); off += (size_t)TOKENS * DIM;
    unsigned char* abuf8 = (unsigned char*)(w + off); off += (size_t)TOKENS * HIDDEN;
    unsigned char* tbuf8 = (unsigned char*)(w + off); off += (size_t)TOKENS * HIDDEN;
    float* x1   = (float*)(w + off); off += (size_t)TOKENS * DIM * 4;

    convert_w8<<<4096, 256, 0, stream>>>(qkv_w, proj_w, fc1_w, eye1_w, eye2_w, fc2_w, w8);

    ln_kernel<<<TOKENS / 4, 256, 0, stream>>>(x, n1w, n1b, hbuf8);

    gemm_f8<4><<<dim3(1152 / 128, TOKENS / 128), 256, 0, stream>>>(
        hbuf8, wqkv8, qkv_b, nullptr, nullptr, nullptr, vtb8, qk8, 1152, 384);

    attn_kernel<<<dim3(SEQ / 128, BATCH * HEADS), 256, 0, stream>>>(qk8, vtb8, obuf8);

    gemm_f8<3><<<dim3(384 / 128, TOKENS / 128), 256, 0, stream>>>(
        obuf8, wproj8, proj_b, x1, x, ls1, nullptr, nullptr, 384, 384);

    ln_kernel<<<TOKENS / 4, 256, 0, stream>>>(x1, n2w, n2b, hbuf8);

    gemm_f8<2><<<dim3(1536 / 128, TOKENS / 128), 256, 0, stream>>>(
        hbuf8, wfc18, fc1_b, nullptr, nullptr, nullptr, nullptr, abuf8, 1536, 384);

    gemm_f8<0><<<dim3(1536 / 128, TOKENS / 128), 256, 0, stream>>>(
        abuf8, weye18, nullptr, nullptr, nullptr, nullptr, nullptr, tbuf8, 1536, 1536);

    gemm_f8<0><<<dim3(1536 / 128, TOKENS / 128), 256, 0, stream>>>(
        tbuf8, weye28, nullptr, nullptr, nullptr, nullptr, nullptr, abuf8, 1536, 1536);

    gemm_f8<3><<<dim3(384 / 128, TOKENS / 128), 256, 0, stream>>>(
        abuf8, wfc28, fc2_b, out, x1, ls2, nullptr, nullptr, 384, 1536);
}